// Round 1
// baseline (949.007 us; speedup 1.0000x reference)
//
#include <hip/hip_runtime.h>
#include <hip/hip_bf16.h>
#include <cstdint>
#include <cstddef>

typedef unsigned short u16;
typedef unsigned int u32;
typedef __attribute__((ext_vector_type(8))) short bf16x8;
typedef __attribute__((ext_vector_type(4))) float f32x4;

static constexpr int Bb = 2, Ll = 2048, Dd = 1024, Hh = 16, Rr = 256, Ee = 8, Ff = 1024;
static constexpr int Tt = Bb * Ll;   // 4096 tokens

__device__ __forceinline__ u16 f2bf(float f){
  union { float f; u32 u; } v; v.f = f;
  u32 u = v.u;
  u32 r = u + 0x7FFFu + ((u >> 16) & 1u);
  return (u16)(r >> 16);
}
__device__ __forceinline__ float bf2f(u16 b){
  union { u32 u; float f; } v; v.u = ((u32)b) << 16; return v.f;
}

// ---------------- transpose + fp32->bf16 convert: src[K,N] f32 -> dst[N,K] bf16 ----------------
__global__ void transpose_conv(const float* __restrict__ src, u16* __restrict__ dst, int K, int N){
  __shared__ float tile[32][33];
  size_t bo = (size_t)blockIdx.z * K * N;
  const float* s = src + bo;
  u16* d = dst + bo;
  int bx = blockIdx.x * 32;   // n
  int by = blockIdx.y * 32;   // k
  int tx = threadIdx.x, ty = threadIdx.y;
  #pragma unroll
  for (int i = ty; i < 32; i += 8) tile[i][tx] = s[(size_t)(by + i) * N + bx + tx];
  __syncthreads();
  #pragma unroll
  for (int i = ty; i < 32; i += 8) d[(size_t)(bx + i) * K + by + tx] = f2bf(tile[tx][i]);
}

// ---------------- rmsnorm: fp32 in -> bf16 out ----------------
template<int DIM>
__global__ void rmsnorm_kernel(const float* __restrict__ x, const float* __restrict__ w,
                               u16* __restrict__ out){
  int t = blockIdx.x;
  const float* xr = x + (size_t)t * DIM;
  u16* orow = out + (size_t)t * DIM;
  int tid = threadIdx.x;
  constexpr int NT = 256;
  constexpr int PER = DIM / NT > 0 ? DIM / NT : 1;
  float vals[PER];
  float ss = 0.f;
  #pragma unroll
  for (int i = 0; i < PER; i++){
    int d = tid + i * NT;
    float v = (d < DIM) ? xr[d] : 0.f;
    vals[i] = v; ss += v * v;
  }
  __shared__ float red[4];
  for (int m = 32; m; m >>= 1) ss += __shfl_xor(ss, m, 64);
  if ((tid & 63) == 0) red[tid >> 6] = ss;
  __syncthreads();
  float tot = red[0] + red[1] + red[2] + red[3];
  float rn = rsqrtf(tot / DIM + 1e-6f);
  #pragma unroll
  for (int i = 0; i < PER; i++){
    int d = tid + i * NT;
    if (d < DIM) orow[d] = f2bf(vals[i] * rn * w[d]);
  }
}

// ---------------- router: fp32 rmsnorm(h)@gate, softmax, top2, bucket counts ----------------
__global__ void router_kernel(const float* __restrict__ h, const float* __restrict__ ln2w,
                              const float* __restrict__ gate,
                              float* __restrict__ probs_out,
                              int* __restrict__ topi, float* __restrict__ topw,
                              int* __restrict__ counts){
  int t = blockIdx.x; int tid = threadIdx.x;
  const float* hr = h + (size_t)t * Dd;
  float v[4]; float ss = 0.f;
  #pragma unroll
  for (int i = 0; i < 4; i++){ float x = hr[tid + i * 256]; v[i] = x; ss += x * x; }
  __shared__ float red[4];
  for (int m = 32; m; m >>= 1) ss += __shfl_xor(ss, m, 64);
  if ((tid & 63) == 0) red[tid >> 6] = ss;
  __syncthreads();
  float rn = rsqrtf((red[0] + red[1] + red[2] + red[3]) / Dd + 1e-6f);
  float p[8];
  #pragma unroll
  for (int e = 0; e < 8; e++) p[e] = 0.f;
  #pragma unroll
  for (int i = 0; i < 4; i++){
    int d = tid + i * 256;
    float hv = v[i] * rn * ln2w[d];
    const float* g = gate + (size_t)d * 8;
    #pragma unroll
    for (int e = 0; e < 8; e++) p[e] += hv * g[e];
  }
  #pragma unroll
  for (int e = 0; e < 8; e++){
    float x = p[e];
    for (int m = 32; m; m >>= 1) x += __shfl_xor(x, m, 64);
    p[e] = x;
  }
  __shared__ float pe[4][8];
  if ((tid & 63) == 0){ for (int e = 0; e < 8; e++) pe[tid >> 6][e] = p[e]; }
  __syncthreads();
  if (tid == 0){
    float lg[8];
    for (int e = 0; e < 8; e++) lg[e] = pe[0][e] + pe[1][e] + pe[2][e] + pe[3][e];
    float mx = lg[0];
    for (int e = 1; e < 8; e++) mx = fmaxf(mx, lg[e]);
    float pr[8]; float s = 0.f;
    for (int e = 0; e < 8; e++){ pr[e] = __expf(lg[e] - mx); s += pr[e]; }
    float inv = 1.f / s;
    for (int e = 0; e < 8; e++) probs_out[(size_t)t * 8 + e] = pr[e] * inv;
    int i0 = 0;
    for (int e = 1; e < 8; e++) if (pr[e] > pr[i0]) i0 = e;
    int i1 = -1;
    for (int e = 0; e < 8; e++){ if (e == i0) continue; if (i1 < 0 || pr[e] > pr[i1]) i1 = e; }
    float w0 = pr[i0], w1 = pr[i1]; float wn = 1.f / (w0 + w1);
    topi[t * 2] = i0; topi[t * 2 + 1] = i1;
    topw[t * 2] = w0 * wn; topw[t * 2 + 1] = w1 * wn;
    atomicAdd(&counts[i0], 1); atomicAdd(&counts[i1], 1);
  }
}

__global__ void scan_kernel(const int* __restrict__ counts, int* __restrict__ offs){
  if (threadIdx.x == 0 && blockIdx.x == 0){
    int c = 0;
    for (int e = 0; e < 8; e++){ offs[e] = c; c += counts[e]; }
  }
}

__global__ void bucket_kernel(const int* __restrict__ topi, const float* __restrict__ topw,
                              const int* __restrict__ offs, int* __restrict__ cur,
                              int* __restrict__ entries, float* __restrict__ ew){
  int t = blockIdx.x * 256 + threadIdx.x;
  if (t >= Tt) return;
  #pragma unroll
  for (int s = 0; s < 2; s++){
    int e = topi[t * 2 + s];
    int pos = offs[e] + atomicAdd(&cur[e], 1);
    entries[pos] = t;
    ew[pos] = topw[t * 2 + s];
  }
}

// ---------------- generic bf16 GEMM: C[M,N] = A[M,K] @ Bt[N,K]^T ----------------
// ROWMODE: 0 dense rows; 1 gather rows via entries (C row = off+r); 2 dense-in-entry-space, scatter epilogue
// MODE: 0 bf16 C; 1 f32 C = acc + res; 2 f32 C; 3 bf16 C = silu(acc)*comp; 4 atomicAdd(out[token], w*acc)
template<int ROWMODE, int MODE>
__launch_bounds__(256, 2)
__global__ void gemm_bt(const u16* __restrict__ A, const u16* __restrict__ Bt,
                        void* __restrict__ C, const float* __restrict__ res,
                        const u16* __restrict__ comp,
                        int M, int N, int K,
                        const int* __restrict__ entries, const float* __restrict__ ew,
                        const int* __restrict__ counts, const int* __restrict__ offs,
                        float* __restrict__ outAt){
  constexpr int LDT = 40;          // LDS row stride (elems), pad to break conflicts
  __shared__ u16 As[128 * LDT];
  __shared__ u16 Bs[128 * LDT];
  __shared__ int els[128];
  __shared__ float ewl[128];

  int e = (ROWMODE ? blockIdx.z : 0);
  const u16* Bte = Bt + (size_t)e * N * K;
  int cnt, off;
  if (ROWMODE == 0){ cnt = M; off = 0; }
  else { cnt = counts[e]; off = offs[e]; }
  int rt = blockIdx.y * 128;
  if (rt >= cnt) return;
  int cb = blockIdx.x * 128;
  int tid = threadIdx.x;

  if (ROWMODE >= 1){
    if (tid < 128){
      int r = rt + tid;
      els[tid] = (r < cnt) ? entries[off + r] : 0;
      if (MODE == 4) ewl[tid] = (r < cnt) ? ew[off + r] : 0.f;
    }
  }

  int w = tid >> 6, lane = tid & 63;
  int wm = w >> 1, wn = w & 1;
  int quad = lane >> 4, l16 = lane & 15;

  f32x4 acc[4][4];
  const f32x4 zf = {0.f, 0.f, 0.f, 0.f};
  #pragma unroll
  for (int i = 0; i < 4; i++)
    #pragma unroll
    for (int j = 0; j < 4; j++) acc[i][j] = zf;

  int nk = K >> 5;
  for (int kk = 0; kk < nk; kk++){
    int k0 = kk << 5;
    __syncthreads();
    // stage A: 128 rows x 32 cols
    #pragma unroll
    for (int c = 0; c < 2; c++){
      int idx = tid + c * 256;
      int r = idx >> 2; int kc = (idx & 3) * 8;
      uint4 val = {0u, 0u, 0u, 0u};
      int rr = rt + r;
      if (rr < cnt){
        size_t arow;
        if (ROWMODE == 0) arow = (size_t)rr;
        else if (ROWMODE == 1) arow = (size_t)els[r];
        else arow = (size_t)(off + rr);
        val = *(const uint4*)(A + arow * K + k0 + kc);
      }
      *(uint4*)&As[r * LDT + kc] = val;
    }
    // stage B
    #pragma unroll
    for (int c = 0; c < 2; c++){
      int idx = tid + c * 256;
      int r = idx >> 2; int kc = (idx & 3) * 8;
      uint4 val = *(const uint4*)(Bte + (size_t)(cb + r) * K + k0 + kc);
      *(uint4*)&Bs[r * LDT + kc] = val;
    }
    __syncthreads();
    bf16x8 af[4], bfr[4];
    #pragma unroll
    for (int mt = 0; mt < 4; mt++)
      af[mt] = *(const bf16x8*)&As[(wm * 64 + mt * 16 + l16) * LDT + quad * 8];
    #pragma unroll
    for (int nt = 0; nt < 4; nt++)
      bfr[nt] = *(const bf16x8*)&Bs[(wn * 64 + nt * 16 + l16) * LDT + quad * 8];
    #pragma unroll
    for (int mt = 0; mt < 4; mt++)
      #pragma unroll
      for (int nt = 0; nt < 4; nt++)
        acc[mt][nt] = __builtin_amdgcn_mfma_f32_16x16x32_bf16(af[mt], bfr[nt], acc[mt][nt], 0, 0, 0);
  }

  // epilogue
  #pragma unroll
  for (int mt = 0; mt < 4; mt++){
    #pragma unroll
    for (int nt = 0; nt < 4; nt++){
      #pragma unroll
      for (int r = 0; r < 4; r++){
        int row = wm * 64 + mt * 16 + quad * 4 + r;
        int col = cb + wn * 64 + nt * 16 + l16;
        int rr = rt + row;
        if (rr >= cnt) continue;
        float v = acc[mt][nt][r];
        if (MODE == 0){
          size_t ci = (size_t)((ROWMODE == 1) ? (off + rr) : rr) * N + col;
          ((u16*)C)[ci] = f2bf(v);
        } else if (MODE == 1){
          size_t ci = (size_t)rr * N + col;
          ((float*)C)[ci] = v + res[ci];
        } else if (MODE == 2){
          size_t ci = (size_t)rr * N + col;
          ((float*)C)[ci] = v;
        } else if (MODE == 3){
          size_t ci = (size_t)((ROWMODE == 1) ? (off + rr) : rr) * N + col;
          float c3 = bf2f(comp[ci]);
          float sv = v / (1.f + __expf(-v));
          ((u16*)C)[ci] = f2bf(sv * c3);
        } else {
          int tok = els[row];
          atomicAdd(&outAt[(size_t)tok * N + col], ewl[row] * v);
        }
      }
    }
  }
}

// ---------------- flash attention, causal, HD=64, Q-tile 64, K-tile 64 ----------------
__launch_bounds__(256, 2)
__global__ void attn_kernel(const u16* __restrict__ q, const u16* __restrict__ kv,
                            u16* __restrict__ out){
  constexpr int LDK = 72;
  __shared__ u16 Ks[64 * LDK];
  __shared__ u16 Vt[64 * LDK];
  __shared__ u16 Ps[64 * LDK];
  int q0 = blockIdx.x * 64;
  int h = blockIdx.y;
  int b = blockIdx.z;
  int tid = threadIdx.x;
  int w = tid >> 6, lane = tid & 63, quad = lane >> 4, l16 = lane & 15;
  size_t bL = (size_t)b * Ll;

  int qrow = q0 + w * 16 + l16;
  bf16x8 qf[2];
  #pragma unroll
  for (int ks = 0; ks < 2; ks++)
    qf[ks] = *(const bf16x8*)(q + (bL + qrow) * 1024 + h * 64 + ks * 32 + quad * 8);

  f32x4 oacc[4];
  const f32x4 zf = {0.f, 0.f, 0.f, 0.f};
  #pragma unroll
  for (int nt = 0; nt < 4; nt++) oacc[nt] = zf;
  float mrow[4], lrow[4];
  #pragma unroll
  for (int r = 0; r < 4; r++){ mrow[r] = -1e30f; lrow[r] = 0.f; }

  for (int kt = 0; kt <= q0; kt += 64){
    __syncthreads();
    // stage K (row-major) and V (transposed)
    #pragma unroll
    for (int c = 0; c < 2; c++){
      int idx = tid + c * 256;
      int r = idx >> 3; int d0 = (idx & 7) * 8;
      uint4 kvv = *(const uint4*)(kv + (bL + kt + r) * 2048 + h * 64 + d0);
      *(uint4*)&Ks[r * LDK + d0] = kvv;
      uint4 vv = *(const uint4*)(kv + (bL + kt + r) * 2048 + 1024 + h * 64 + d0);
      const u16* pv = (const u16*)&vv;
      #pragma unroll
      for (int j = 0; j < 8; j++) Vt[(d0 + j) * LDK + r] = pv[j];
    }
    __syncthreads();
    // S = Q K^T
    f32x4 sacc[4];
    #pragma unroll
    for (int nt = 0; nt < 4; nt++) sacc[nt] = zf;
    #pragma unroll
    for (int nt = 0; nt < 4; nt++){
      #pragma unroll
      for (int ks = 0; ks < 2; ks++){
        bf16x8 kf = *(const bf16x8*)&Ks[(nt * 16 + l16) * LDK + ks * 32 + quad * 8];
        sacc[nt] = __builtin_amdgcn_mfma_f32_16x16x32_bf16(qf[ks], kf, sacc[nt], 0, 0, 0);
      }
    }
    bool diag = (kt == q0);
    float sv[4][4], mx[4];
    #pragma unroll
    for (int r = 0; r < 4; r++) mx[r] = -1e30f;
    #pragma unroll
    for (int nt = 0; nt < 4; nt++){
      #pragma unroll
      for (int r = 0; r < 4; r++){
        float s = sacc[nt][r] * 0.125f;
        if (diag){
          int row = w * 16 + quad * 4 + r;
          int col = nt * 16 + l16;
          if (col > row) s = -1e30f;
        }
        sv[nt][r] = s;
        mx[r] = fmaxf(mx[r], s);
      }
    }
    #pragma unroll
    for (int r = 0; r < 4; r++){
      float m = mx[r];
      for (int msk = 1; msk < 16; msk <<= 1) m = fmaxf(m, __shfl_xor(m, msk, 64));
      mx[r] = m;
    }
    float alpha[4];
    #pragma unroll
    for (int r = 0; r < 4; r++){
      float mn = fmaxf(mrow[r], mx[r]);
      alpha[r] = __expf(mrow[r] - mn);
      mrow[r] = mn;
    }
    float rsum[4] = {0.f, 0.f, 0.f, 0.f};
    #pragma unroll
    for (int nt = 0; nt < 4; nt++){
      #pragma unroll
      for (int r = 0; r < 4; r++){
        float p = __expf(sv[nt][r] - mrow[r]);
        rsum[r] += p;
        Ps[(w * 16 + quad * 4 + r) * LDK + nt * 16 + l16] = f2bf(p);
      }
    }
    #pragma unroll
    for (int r = 0; r < 4; r++){
      float s = rsum[r];
      for (int msk = 1; msk < 16; msk <<= 1) s += __shfl_xor(s, msk, 64);
      lrow[r] = lrow[r] * alpha[r] + s;
      #pragma unroll
      for (int nt = 0; nt < 4; nt++) oacc[nt][r] *= alpha[r];
    }
    __syncthreads();
    // O += P V
    #pragma unroll
    for (int ks = 0; ks < 2; ks++){
      bf16x8 pf = *(const bf16x8*)&Ps[(w * 16 + l16) * LDK + ks * 32 + quad * 8];
      #pragma unroll
      for (int nt = 0; nt < 4; nt++){
        bf16x8 vf = *(const bf16x8*)&Vt[(nt * 16 + l16) * LDK + ks * 32 + quad * 8];
        oacc[nt] = __builtin_amdgcn_mfma_f32_16x16x32_bf16(pf, vf, oacc[nt], 0, 0, 0);
      }
    }
  }
  #pragma unroll
  for (int nt = 0; nt < 4; nt++){
    #pragma unroll
    for (int r = 0; r < 4; r++){
      int row = q0 + w * 16 + quad * 4 + r;
      float o = oacc[nt][r] / lrow[r];
      out[(bL + row) * 1024 + h * 64 + nt * 16 + l16] = f2bf(o);
    }
  }
}

// ---------------- host launch ----------------
extern "C" void kernel_launch(void* const* d_in, const int* in_sizes, int n_in,
                              void* d_out, int out_size, void* d_ws, size_t ws_size,
                              hipStream_t stream){
  const float* x     = (const float*)d_in[0];
  const float* ln1_w = (const float*)d_in[1];
  const float* q_w   = (const float*)d_in[2];
  const float* kvd_w = (const float*)d_in[3];
  const float* kvn_w = (const float*)d_in[4];
  const float* kvu_w = (const float*)d_in[5];
  const float* o_w   = (const float*)d_in[6];
  const float* ln2_w = (const float*)d_in[7];
  const float* gate_w= (const float*)d_in[8];
  const float* sh_w1 = (const float*)d_in[9];
  const float* sh_w2 = (const float*)d_in[10];
  const float* sh_w3 = (const float*)d_in[11];
  const float* re_w1 = (const float*)d_in[12];
  const float* re_w2 = (const float*)d_in[13];
  const float* re_w3 = (const float*)d_in[14];
  float* out = (float*)d_out;

  char* wp = (char*)d_ws;
  auto alloc = [&](size_t bytes)->char*{
    char* p = wp; wp += (bytes + 255) & ~(size_t)255; return p;
  };
  u16* qT    = (u16*)alloc((size_t)1024 * 1024 * 2);
  u16* kvdT  = (u16*)alloc((size_t)256 * 1024 * 2);
  u16* kvuT  = (u16*)alloc((size_t)2048 * 256 * 2);
  u16* oT    = (u16*)alloc((size_t)1024 * 1024 * 2);
  u16* sh1T  = (u16*)alloc((size_t)1024 * 1024 * 2);
  u16* sh2T  = (u16*)alloc((size_t)1024 * 1024 * 2);
  u16* sh3T  = (u16*)alloc((size_t)1024 * 1024 * 2);
  u16* re1T  = (u16*)alloc((size_t)8 * 1024 * 1024 * 2);
  u16* re2T  = (u16*)alloc((size_t)8 * 1024 * 1024 * 2);
  u16* re3T  = (u16*)alloc((size_t)8 * 1024 * 1024 * 2);
  u16* xn    = (u16*)alloc((size_t)Tt * 1024 * 2);   // also hn after attention phase
  u16* qact  = (u16*)alloc((size_t)Tt * 1024 * 2);   // also tmp3 (h3 of shared)
  float* latpre = (float*)alloc((size_t)Tt * 256 * 4);
  u16* lat   = (u16*)alloc((size_t)Tt * 256 * 2);
  u16* kvbuf = (u16*)alloc((size_t)Tt * 2048 * 2);   // also gr (routed g) [8192,1024]
  u16* attnb = (u16*)alloc((size_t)Tt * 1024 * 2);   // also g (shared expert gate)
  float* hbuf = (float*)alloc((size_t)Tt * 1024 * 4);
  u16* r3    = (u16*)alloc((size_t)Tt * 2 * 1024 * 2);
  int* counts = (int*)alloc(32);
  int* cur    = (int*)alloc(32);
  int* offs   = (int*)alloc(32);
  int* topi   = (int*)alloc((size_t)Tt * 2 * 4);
  float* topw = (float*)alloc((size_t)Tt * 2 * 4);
  int* entries= (int*)alloc((size_t)Tt * 2 * 4);
  float* ewt  = (float*)alloc((size_t)Tt * 2 * 4);
  (void)ws_size; (void)n_in; (void)in_sizes; (void)out_size;

  hipMemsetAsync(counts, 0, 32, stream);
  hipMemsetAsync(cur, 0, 32, stream);

  dim3 tb(32, 8);
  transpose_conv<<<dim3(32, 32, 1), tb, 0, stream>>>(q_w,   qT,   1024, 1024);
  transpose_conv<<<dim3(8,  32, 1), tb, 0, stream>>>(kvd_w, kvdT, 1024, 256);
  transpose_conv<<<dim3(64, 8,  1), tb, 0, stream>>>(kvu_w, kvuT, 256,  2048);
  transpose_conv<<<dim3(32, 32, 1), tb, 0, stream>>>(o_w,   oT,   1024, 1024);
  transpose_conv<<<dim3(32, 32, 1), tb, 0, stream>>>(sh_w1, sh1T, 1024, 1024);
  transpose_conv<<<dim3(32, 32, 1), tb, 0, stream>>>(sh_w2, sh2T, 1024, 1024);
  transpose_conv<<<dim3(32, 32, 1), tb, 0, stream>>>(sh_w3, sh3T, 1024, 1024);
  transpose_conv<<<dim3(32, 32, 8), tb, 0, stream>>>(re_w1, re1T, 1024, 1024);
  transpose_conv<<<dim3(32, 32, 8), tb, 0, stream>>>(re_w2, re2T, 1024, 1024);
  transpose_conv<<<dim3(32, 32, 8), tb, 0, stream>>>(re_w3, re3T, 1024, 1024);

  // xn = rmsnorm(x, ln1_w)
  rmsnorm_kernel<1024><<<Tt, 256, 0, stream>>>(x, ln1_w, xn);

  // q = xn @ q_w ; latent_pre = xn @ kvd_w
  gemm_bt<0,0><<<dim3(8, 32), 256, 0, stream>>>(xn, qT, qact, nullptr, nullptr,
      Tt, 1024, 1024, nullptr, nullptr, nullptr, nullptr, nullptr);
  gemm_bt<0,2><<<dim3(2, 32), 256, 0, stream>>>(xn, kvdT, latpre, nullptr, nullptr,
      Tt, 256, 1024, nullptr, nullptr, nullptr, nullptr, nullptr);
  rmsnorm_kernel<256><<<Tt, 256, 0, stream>>>(latpre, kvn_w, lat);
  // kv = latent @ kvu_w
  gemm_bt<0,0><<<dim3(16, 32), 256, 0, stream>>>(lat, kvuT, kvbuf, nullptr, nullptr,
      Tt, 2048, 256, nullptr, nullptr, nullptr, nullptr, nullptr);
  // attention
  attn_kernel<<<dim3(32, 16, 2), 256, 0, stream>>>(qact, kvbuf, attnb);
  // h = x + attn_out @ o_w
  gemm_bt<0,1><<<dim3(8, 32), 256, 0, stream>>>(attnb, oT, hbuf, x, nullptr,
      Tt, 1024, 1024, nullptr, nullptr, nullptr, nullptr, nullptr);
  // hn = rmsnorm(h, ln2_w)  (reuse xn buffer)
  rmsnorm_kernel<1024><<<Tt, 256, 0, stream>>>(hbuf, ln2_w, xn);
  // router (fp32 from h), probs -> d_out tail
  router_kernel<<<Tt, 256, 0, stream>>>(hbuf, ln2_w, gate_w, out + (size_t)Tt * Dd,
                                        topi, topw, counts);
  scan_kernel<<<1, 64, 0, stream>>>(counts, offs);
  bucket_kernel<<<16, 256, 0, stream>>>(topi, topw, offs, cur, entries, ewt);

  // shared expert: tmp3 = hn @ sh_w3 (into qact), g = silu(hn @ sh_w1) * tmp3 (into attnb)
  gemm_bt<0,0><<<dim3(8, 32), 256, 0, stream>>>(xn, sh3T, qact, nullptr, nullptr,
      Tt, 1024, 1024, nullptr, nullptr, nullptr, nullptr, nullptr);
  gemm_bt<0,3><<<dim3(8, 32), 256, 0, stream>>>(xn, sh1T, attnb, nullptr, qact,
      Tt, 1024, 1024, nullptr, nullptr, nullptr, nullptr, nullptr);
  // d_out = h + g @ sh_w2
  gemm_bt<0,1><<<dim3(8, 32), 256, 0, stream>>>(attnb, sh2T, out, hbuf, nullptr,
      Tt, 1024, 1024, nullptr, nullptr, nullptr, nullptr, nullptr);

  // routed experts (gathered): r3 = Xg @ re_w3[e]; gr = silu(Xg @ re_w1[e]) * r3 (into kvbuf)
  gemm_bt<1,0><<<dim3(8, 32, 8), 256, 0, stream>>>(xn, re3T, r3, nullptr, nullptr,
      Tt, 1024, 1024, entries, nullptr, counts, offs, nullptr);
  gemm_bt<1,3><<<dim3(8, 32, 8), 256, 0, stream>>>(xn, re1T, kvbuf, nullptr, r3,
      Tt, 1024, 1024, entries, nullptr, counts, offs, nullptr);
  // d_out += w * (gr @ re_w2[e])  (scatter atomic)
  gemm_bt<2,4><<<dim3(8, 32, 8), 256, 0, stream>>>(kvbuf, re2T, nullptr, nullptr, nullptr,
      Tt, 1024, 1024, entries, ewt, counts, offs, out);
}

// Round 2
// 840.529 us; speedup vs baseline: 1.1291x; 1.1291x over previous
//
#include <hip/hip_runtime.h>
#include <hip/hip_bf16.h>
#include <cstdint>
#include <cstddef>

typedef unsigned short u16;
typedef unsigned int u32;
typedef __attribute__((ext_vector_type(8))) short bf16x8;
typedef __attribute__((ext_vector_type(4))) float f32x4;

static constexpr int Bb = 2, Ll = 2048, Dd = 1024, Hh = 16, Rr = 256, Ee = 8, Ff = 1024;
static constexpr int Tt = Bb * Ll;   // 4096 tokens

__device__ __forceinline__ u16 f2bf(float f){
  union { float f; u32 u; } v; v.f = f;
  u32 u = v.u;
  u32 r = u + 0x7FFFu + ((u >> 16) & 1u);
  return (u16)(r >> 16);
}
__device__ __forceinline__ float bf2f(u16 b){
  union { u32 u; float f; } v; v.u = ((u32)b) << 16; return v.f;
}

// async global->LDS, 16B per lane. LDS dest must be wave-uniform base + lane*16.
#define GLDS(gp, lp) __builtin_amdgcn_global_load_lds( \
    (const __attribute__((address_space(1))) unsigned int*)(gp), \
    (__attribute__((address_space(3))) unsigned int*)(lp), 16, 0, 0)

// ---------------- transpose + fp32->bf16 convert: src[K,N] f32 -> dst[N,K] bf16 ----------------
__global__ void transpose_conv(const float* __restrict__ src, u16* __restrict__ dst, int K, int N){
  __shared__ float tile[32][33];
  size_t bo = (size_t)blockIdx.z * K * N;
  const float* s = src + bo;
  u16* d = dst + bo;
  int bx = blockIdx.x * 32;   // n
  int by = blockIdx.y * 32;   // k
  int tx = threadIdx.x, ty = threadIdx.y;
  #pragma unroll
  for (int i = ty; i < 32; i += 8) tile[i][tx] = s[(size_t)(by + i) * N + bx + tx];
  __syncthreads();
  #pragma unroll
  for (int i = ty; i < 32; i += 8) d[(size_t)(bx + i) * K + by + tx] = f2bf(tile[tx][i]);
}

// ---------------- rmsnorm: fp32 in -> bf16 out ----------------
template<int DIM>
__global__ void rmsnorm_kernel(const float* __restrict__ x, const float* __restrict__ w,
                               u16* __restrict__ out){
  int t = blockIdx.x;
  const float* xr = x + (size_t)t * DIM;
  u16* orow = out + (size_t)t * DIM;
  int tid = threadIdx.x;
  constexpr int NT = 256;
  constexpr int PER = DIM / NT > 0 ? DIM / NT : 1;
  float vals[PER];
  float ss = 0.f;
  #pragma unroll
  for (int i = 0; i < PER; i++){
    int d = tid + i * NT;
    float v = (d < DIM) ? xr[d] : 0.f;
    vals[i] = v; ss += v * v;
  }
  __shared__ float red[4];
  for (int m = 32; m; m >>= 1) ss += __shfl_xor(ss, m, 64);
  if ((tid & 63) == 0) red[tid >> 6] = ss;
  __syncthreads();
  float tot = red[0] + red[1] + red[2] + red[3];
  float rn = rsqrtf(tot / DIM + 1e-6f);
  #pragma unroll
  for (int i = 0; i < PER; i++){
    int d = tid + i * NT;
    if (d < DIM) orow[d] = f2bf(vals[i] * rn * w[d]);
  }
}

// ---------------- router ----------------
__global__ void router_kernel(const float* __restrict__ h, const float* __restrict__ ln2w,
                              const float* __restrict__ gate,
                              float* __restrict__ probs_out,
                              int* __restrict__ topi, float* __restrict__ topw,
                              int* __restrict__ counts){
  int t = blockIdx.x; int tid = threadIdx.x;
  const float* hr = h + (size_t)t * Dd;
  float v[4]; float ss = 0.f;
  #pragma unroll
  for (int i = 0; i < 4; i++){ float x = hr[tid + i * 256]; v[i] = x; ss += x * x; }
  __shared__ float red[4];
  for (int m = 32; m; m >>= 1) ss += __shfl_xor(ss, m, 64);
  if ((tid & 63) == 0) red[tid >> 6] = ss;
  __syncthreads();
  float rn = rsqrtf((red[0] + red[1] + red[2] + red[3]) / Dd + 1e-6f);
  float p[8];
  #pragma unroll
  for (int e = 0; e < 8; e++) p[e] = 0.f;
  #pragma unroll
  for (int i = 0; i < 4; i++){
    int d = tid + i * 256;
    float hv = v[i] * rn * ln2w[d];
    const float* g = gate + (size_t)d * 8;
    #pragma unroll
    for (int e = 0; e < 8; e++) p[e] += hv * g[e];
  }
  #pragma unroll
  for (int e = 0; e < 8; e++){
    float x = p[e];
    for (int m = 32; m; m >>= 1) x += __shfl_xor(x, m, 64);
    p[e] = x;
  }
  __shared__ float pe[4][8];
  if ((tid & 63) == 0){ for (int e = 0; e < 8; e++) pe[tid >> 6][e] = p[e]; }
  __syncthreads();
  if (tid == 0){
    float lg[8];
    for (int e = 0; e < 8; e++) lg[e] = pe[0][e] + pe[1][e] + pe[2][e] + pe[3][e];
    float mx = lg[0];
    for (int e = 1; e < 8; e++) mx = fmaxf(mx, lg[e]);
    float pr[8]; float s = 0.f;
    for (int e = 0; e < 8; e++){ pr[e] = __expf(lg[e] - mx); s += pr[e]; }
    float inv = 1.f / s;
    for (int e = 0; e < 8; e++) probs_out[(size_t)t * 8 + e] = pr[e] * inv;
    int i0 = 0;
    for (int e = 1; e < 8; e++) if (pr[e] > pr[i0]) i0 = e;
    int i1 = -1;
    for (int e = 0; e < 8; e++){ if (e == i0) continue; if (i1 < 0 || pr[e] > pr[i1]) i1 = e; }
    float w0 = pr[i0], w1 = pr[i1]; float wn = 1.f / (w0 + w1);
    topi[t * 2] = i0; topi[t * 2 + 1] = i1;
    topw[t * 2] = w0 * wn; topw[t * 2 + 1] = w1 * wn;
    atomicAdd(&counts[i0], 1); atomicAdd(&counts[i1], 1);
  }
}

__global__ void scan_kernel(const int* __restrict__ counts, int* __restrict__ offs){
  if (threadIdx.x == 0 && blockIdx.x == 0){
    int c = 0;
    for (int e = 0; e < 8; e++){ offs[e] = c; c += counts[e]; }
  }
}

__global__ void bucket_kernel(const int* __restrict__ topi, const float* __restrict__ topw,
                              const int* __restrict__ offs, int* __restrict__ cur,
                              int* __restrict__ entries, float* __restrict__ ew){
  int t = blockIdx.x * 256 + threadIdx.x;
  if (t >= Tt) return;
  #pragma unroll
  for (int s = 0; s < 2; s++){
    int e = topi[t * 2 + s];
    int pos = offs[e] + atomicAdd(&cur[e], 1);
    entries[pos] = t;
    ew[pos] = topw[t * 2 + s];
  }
}

// ---------------- bf16 GEMM, m97 structure: 128x128 tile, BK=32, global_load_lds ----------------
// ROWMODE: 0 dense; 1 gather rows via entries; 2 dense-in-entry-space (A row = off+r)
// MODE: 0 bf16 C; 1 f32 C = acc + res; 2 f32 C; 3 bf16 C = silu(acc)*comp; 4 atomicAdd(out[token], w*acc)
template<int ROWMODE, int MODE>
__launch_bounds__(256)
__global__ void gemm_bt(const u16* __restrict__ A, const u16* __restrict__ Bt,
                        void* __restrict__ C, const float* __restrict__ res,
                        const u16* __restrict__ comp,
                        int M, int N, int K,
                        const int* __restrict__ entries, const float* __restrict__ ew,
                        const int* __restrict__ counts, const int* __restrict__ offs,
                        float* __restrict__ outAt){
  __shared__ __align__(16) u16 As[128 * 32];
  __shared__ __align__(16) u16 Bs[128 * 32];
  __shared__ int els[128];
  __shared__ float ewl[128];

  int e = (ROWMODE ? blockIdx.z : 0);
  const u16* Bte = Bt + (size_t)e * N * K;
  int cnt, off;
  if (ROWMODE == 0){ cnt = M; off = 0; }
  else { cnt = counts[e]; off = offs[e]; }
  int rt = blockIdx.y * 128;
  if (rt >= cnt) return;
  int cb = blockIdx.x * 128;
  int tid = threadIdx.x;

  if (ROWMODE >= 1){
    if (tid < 128){
      int r = rt + tid;
      els[tid] = (r < cnt) ? entries[off + r] : 0;
      ewl[tid] = (MODE == 4 && r < cnt) ? ew[off + r] : 0.f;
    }
    __syncthreads();
  }

  int sr = tid >> 2;            // 0..63: staged row within half-tile
  int skc = (tid & 3) * 8;      // k-col offset (elements)
  int rr0 = rt + sr, rr1 = rt + sr + 64;
  size_t ar0, ar1; bool ok0, ok1;
  if (ROWMODE == 0){ ar0 = (size_t)rr0; ar1 = (size_t)rr1; ok0 = ok1 = true; }
  else if (ROWMODE == 1){ ok0 = rr0 < cnt; ok1 = rr1 < cnt;
                          ar0 = (size_t)els[sr]; ar1 = (size_t)els[sr + 64]; }
  else { ar0 = (size_t)off + rr0; ar1 = (size_t)off + rr1; ok0 = ok1 = true; }
  const u16* pa0 = A + ar0 * K + skc;
  const u16* pa1 = A + ar1 * K + skc;
  const u16* pb0 = Bte + (size_t)(cb + sr) * K + skc;
  const u16* pb1 = Bte + (size_t)(cb + sr + 64) * K + skc;
  u16* lA0 = &As[tid * 8];
  u16* lA1 = &As[2048 + tid * 8];
  u16* lB0 = &Bs[tid * 8];
  u16* lB1 = &Bs[2048 + tid * 8];

  int w = tid >> 6, lane = tid & 63;
  int wm = w >> 1, wn = w & 1;
  int quad = lane >> 4, l16 = lane & 15;

  f32x4 acc[4][4];
  const f32x4 zf = {0.f, 0.f, 0.f, 0.f};
  #pragma unroll
  for (int i = 0; i < 4; i++)
    #pragma unroll
    for (int j = 0; j < 4; j++) acc[i][j] = zf;

  for (int k0 = 0; k0 < K; k0 += 32){
    __syncthreads();
    if (ok0) GLDS(pa0 + k0, lA0);
    if (ok1) GLDS(pa1 + k0, lA1);
    GLDS(pb0 + k0, lB0);
    GLDS(pb1 + k0, lB1);
    __syncthreads();
    bf16x8 af[4], bfr[4];
    #pragma unroll
    for (int mt = 0; mt < 4; mt++)
      af[mt] = *(const bf16x8*)&As[(wm * 64 + mt * 16 + l16) * 32 + quad * 8];
    #pragma unroll
    for (int nt = 0; nt < 4; nt++)
      bfr[nt] = *(const bf16x8*)&Bs[(wn * 64 + nt * 16 + l16) * 32 + quad * 8];
    #pragma unroll
    for (int mt = 0; mt < 4; mt++)
      #pragma unroll
      for (int nt = 0; nt < 4; nt++)
        acc[mt][nt] = __builtin_amdgcn_mfma_f32_16x16x32_bf16(af[mt], bfr[nt], acc[mt][nt], 0, 0, 0);
  }

  // epilogue
  #pragma unroll
  for (int mt = 0; mt < 4; mt++){
    #pragma unroll
    for (int nt = 0; nt < 4; nt++){
      #pragma unroll
      for (int r = 0; r < 4; r++){
        int row = wm * 64 + mt * 16 + quad * 4 + r;
        int col = cb + wn * 64 + nt * 16 + l16;
        int rr = rt + row;
        if (rr >= cnt) continue;
        float v = acc[mt][nt][r];
        if (MODE == 0){
          size_t ci = (size_t)((ROWMODE == 1) ? (off + rr) : rr) * N + col;
          ((u16*)C)[ci] = f2bf(v);
        } else if (MODE == 1){
          size_t ci = (size_t)rr * N + col;
          ((float*)C)[ci] = v + res[ci];
        } else if (MODE == 2){
          size_t ci = (size_t)rr * N + col;
          ((float*)C)[ci] = v;
        } else if (MODE == 3){
          size_t ci = (size_t)((ROWMODE == 1) ? (off + rr) : rr) * N + col;
          float c3 = bf2f(comp[ci]);
          float sv = v / (1.f + __expf(-v));
          ((u16*)C)[ci] = f2bf(sv * c3);
        } else {
          int tok = els[row];
          atomicAdd(&outAt[(size_t)tok * N + col], ewl[row] * v);
        }
      }
    }
  }
}

// ---------------- per-(b,h) V transpose: kv v-part [L,64] -> vt [64,L] ----------------
__global__ void vt_kernel(const u16* __restrict__ kv, u16* __restrict__ vt){
  __shared__ __align__(16) u16 t[64 * 72];
  int kt = blockIdx.x * 64, h = blockIdx.y, b = blockIdx.z;
  size_t bL = (size_t)b * Ll;
  int tid = threadIdx.x;
  int r = tid >> 2, c0 = (tid & 3) * 16;
  const u16* src = kv + (bL + kt + r) * 2048 + 1024 + h * 64 + c0;
  *(uint4*)&t[r * 72 + c0]     = *(const uint4*)(src);
  *(uint4*)&t[r * 72 + c0 + 8] = *(const uint4*)(src + 8);
  __syncthreads();
  int d = tid >> 2; int k0 = (tid & 3) * 16;
  u16 tmp[16];
  #pragma unroll
  for (int j = 0; j < 16; j++) tmp[j] = t[(k0 + j) * 72 + d];
  u16* dst = vt + ((size_t)(b * Hh + h) * 64 + d) * (size_t)Ll + kt + k0;
  *(uint4*)dst       = *(const uint4*)&tmp[0];
  *(uint4*)(dst + 8) = *(const uint4*)&tmp[8];
}

// ---------------- flash attention via S^T = K Q^T, O^T = V^T P ----------------
// wave w owns q-band w*16..w*16+15 (q = lane&15 in all fragments/acc).
__launch_bounds__(256)
__global__ void attn_kernel(const u16* __restrict__ q, const u16* __restrict__ kv,
                            const u16* __restrict__ vt, u16* __restrict__ out){
  constexpr int LD = 72;
  __shared__ __align__(16) u16 Ks[64 * LD];
  __shared__ __align__(16) u16 Vs[64 * LD];
  __shared__ __align__(16) u16 Ps[64 * LD];
  int q0 = blockIdx.x * 64, h = blockIdx.y, b = blockIdx.z;
  size_t bL = (size_t)b * Ll;
  int tid = threadIdx.x, w = tid >> 6, lane = tid & 63, quad = lane >> 4, l16 = lane & 15;
  int qrow = q0 + w * 16 + l16;

  bf16x8 qf[2];
  #pragma unroll
  for (int ks = 0; ks < 2; ks++)
    qf[ks] = *(const bf16x8*)(q + (bL + qrow) * 1024 + h * 64 + ks * 32 + quad * 8);

  f32x4 oacc[4];
  const f32x4 zf = {0.f, 0.f, 0.f, 0.f};
  #pragma unroll
  for (int dt = 0; dt < 4; dt++) oacc[dt] = zf;
  float mprev = -1e30f, lsum = 0.f;

  int sr = tid >> 2, sc = (tid & 3) * 16;
  const u16* kbase = kv + (bL + sr) * 2048 + h * 64 + sc;
  const u16* vbase = vt + ((size_t)(b * Hh + h) * 64 + sr) * (size_t)Ll + sc;

  for (int kt = 0; kt <= q0; kt += 64){
    __syncthreads();
    {
      const u16* kp = kbase + (size_t)kt * 2048;
      *(uint4*)&Ks[sr * LD + sc]     = *(const uint4*)(kp);
      *(uint4*)&Ks[sr * LD + sc + 8] = *(const uint4*)(kp + 8);
      const u16* vp = vbase + kt;
      *(uint4*)&Vs[sr * LD + sc]     = *(const uint4*)(vp);
      *(uint4*)&Vs[sr * LD + sc + 8] = *(const uint4*)(vp + 8);
    }
    __syncthreads();

    // S^T tile: rows = key (64), cols = q (this wave's 16)
    f32x4 sacc[4];
    #pragma unroll
    for (int mt = 0; mt < 4; mt++) sacc[mt] = zf;
    #pragma unroll
    for (int ks = 0; ks < 2; ks++){
      #pragma unroll
      for (int mt = 0; mt < 4; mt++){
        bf16x8 kf = *(const bf16x8*)&Ks[(mt * 16 + l16) * LD + ks * 32 + quad * 8];
        sacc[mt] = __builtin_amdgcn_mfma_f32_16x16x32_bf16(kf, qf[ks], sacc[mt], 0, 0, 0);
      }
    }
    bool diag = (kt == q0);
    int lq = w * 16 + l16;           // local q index
    float sv[16]; float mx = -1e30f;
    #pragma unroll
    for (int mt = 0; mt < 4; mt++){
      #pragma unroll
      for (int r = 0; r < 4; r++){
        float s = sacc[mt][r] * 0.125f;
        if (diag && (mt * 16 + quad * 4 + r > lq)) s = -1e30f;
        sv[mt * 4 + r] = s;
        mx = fmaxf(mx, s);
      }
    }
    mx = fmaxf(mx, __shfl_xor(mx, 16, 64));
    mx = fmaxf(mx, __shfl_xor(mx, 32, 64));
    float mnew = fmaxf(mprev, mx);
    float alpha = __expf(mprev - mnew);
    mprev = mnew;
    float rs = 0.f;
    #pragma unroll
    for (int mt = 0; mt < 4; mt++){
      ushort4 pk;
      float p0 = __expf(sv[mt * 4 + 0] - mnew);
      float p1 = __expf(sv[mt * 4 + 1] - mnew);
      float p2 = __expf(sv[mt * 4 + 2] - mnew);
      float p3 = __expf(sv[mt * 4 + 3] - mnew);
      rs += p0 + p1 + p2 + p3;
      pk.x = f2bf(p0); pk.y = f2bf(p1); pk.z = f2bf(p2); pk.w = f2bf(p3);
      *(ushort4*)&Ps[(w * 16 + l16) * LD + mt * 16 + quad * 4] = pk;
    }
    rs += __shfl_xor(rs, 16, 64);
    rs += __shfl_xor(rs, 32, 64);
    lsum = lsum * alpha + rs;
    #pragma unroll
    for (int dt = 0; dt < 4; dt++) oacc[dt] *= alpha;

    // O^T += V^T P : A = Vs rows d, B = Ps rows q (per-wave region, no barrier needed)
    #pragma unroll
    for (int ks = 0; ks < 2; ks++){
      bf16x8 pf = *(const bf16x8*)&Ps[(w * 16 + l16) * LD + ks * 32 + quad * 8];
      #pragma unroll
      for (int dt = 0; dt < 4; dt++){
        bf16x8 vf = *(const bf16x8*)&Vs[(dt * 16 + l16) * LD + ks * 32 + quad * 8];
        oacc[dt] = __builtin_amdgcn_mfma_f32_16x16x32_bf16(vf, pf, oacc[dt], 0, 0, 0);
      }
    }
  }

  float inv = 1.f / lsum;
  #pragma unroll
  for (int dt = 0; dt < 4; dt++){
    ushort4 ov;
    ov.x = f2bf(oacc[dt][0] * inv);
    ov.y = f2bf(oacc[dt][1] * inv);
    ov.z = f2bf(oacc[dt][2] * inv);
    ov.w = f2bf(oacc[dt][3] * inv);
    *(ushort4*)(out + (bL + qrow) * 1024 + h * 64 + dt * 16 + quad * 4) = ov;
  }
}

// ---------------- host launch ----------------
extern "C" void kernel_launch(void* const* d_in, const int* in_sizes, int n_in,
                              void* d_out, int out_size, void* d_ws, size_t ws_size,
                              hipStream_t stream){
  const float* x     = (const float*)d_in[0];
  const float* ln1_w = (const float*)d_in[1];
  const float* q_w   = (const float*)d_in[2];
  const float* kvd_w = (const float*)d_in[3];
  const float* kvn_w = (const float*)d_in[4];
  const float* kvu_w = (const float*)d_in[5];
  const float* o_w   = (const float*)d_in[6];
  const float* ln2_w = (const float*)d_in[7];
  const float* gate_w= (const float*)d_in[8];
  const float* sh_w1 = (const float*)d_in[9];
  const float* sh_w2 = (const float*)d_in[10];
  const float* sh_w3 = (const float*)d_in[11];
  const float* re_w1 = (const float*)d_in[12];
  const float* re_w2 = (const float*)d_in[13];
  const float* re_w3 = (const float*)d_in[14];
  float* out = (float*)d_out;

  char* wp = (char*)d_ws;
  auto alloc = [&](size_t bytes)->char*{
    char* p = wp; wp += (bytes + 255) & ~(size_t)255; return p;
  };
  u16* qT    = (u16*)alloc((size_t)1024 * 1024 * 2);
  u16* kvdT  = (u16*)alloc((size_t)256 * 1024 * 2);
  u16* kvuT  = (u16*)alloc((size_t)2048 * 256 * 2);
  u16* oT    = (u16*)alloc((size_t)1024 * 1024 * 2);
  u16* sh1T  = (u16*)alloc((size_t)1024 * 1024 * 2);
  u16* sh2T  = (u16*)alloc((size_t)1024 * 1024 * 2);
  u16* sh3T  = (u16*)alloc((size_t)1024 * 1024 * 2);
  u16* re1T  = (u16*)alloc((size_t)8 * 1024 * 1024 * 2);
  u16* re2T  = (u16*)alloc((size_t)8 * 1024 * 1024 * 2);
  u16* re3T  = (u16*)alloc((size_t)8 * 1024 * 1024 * 2);
  u16* xn    = (u16*)alloc((size_t)Tt * 1024 * 2);   // also hn after attention phase
  u16* qact  = (u16*)alloc((size_t)Tt * 1024 * 2);   // also tmp3 (h3 of shared)
  float* latpre = (float*)alloc((size_t)Tt * 256 * 4);
  u16* lat   = (u16*)alloc((size_t)Tt * 256 * 2);
  u16* kvbuf = (u16*)alloc((size_t)Tt * 2048 * 2);   // also gr (routed g) [8192,1024]
  u16* attnb = (u16*)alloc((size_t)Tt * 1024 * 2);   // also g (shared expert gate)
  float* hbuf = (float*)alloc((size_t)Tt * 1024 * 4);
  u16* r3    = (u16*)alloc((size_t)Tt * 2 * 1024 * 2);
  u16* vtb   = (u16*)alloc((size_t)Bb * Hh * 64 * Ll * 2);
  int* counts = (int*)alloc(32);
  int* cur    = (int*)alloc(32);
  int* offs   = (int*)alloc(32);
  int* topi   = (int*)alloc((size_t)Tt * 2 * 4);
  float* topw = (float*)alloc((size_t)Tt * 2 * 4);
  int* entries= (int*)alloc((size_t)Tt * 2 * 4);
  float* ewt  = (float*)alloc((size_t)Tt * 2 * 4);
  (void)ws_size; (void)n_in; (void)in_sizes; (void)out_size;

  hipMemsetAsync(counts, 0, 32, stream);
  hipMemsetAsync(cur, 0, 32, stream);

  dim3 tb(32, 8);
  transpose_conv<<<dim3(32, 32, 1), tb, 0, stream>>>(q_w,   qT,   1024, 1024);
  transpose_conv<<<dim3(8,  32, 1), tb, 0, stream>>>(kvd_w, kvdT, 1024, 256);
  transpose_conv<<<dim3(64, 8,  1), tb, 0, stream>>>(kvu_w, kvuT, 256,  2048);
  transpose_conv<<<dim3(32, 32, 1), tb, 0, stream>>>(o_w,   oT,   1024, 1024);
  transpose_conv<<<dim3(32, 32, 1), tb, 0, stream>>>(sh_w1, sh1T, 1024, 1024);
  transpose_conv<<<dim3(32, 32, 1), tb, 0, stream>>>(sh_w2, sh2T, 1024, 1024);
  transpose_conv<<<dim3(32, 32, 1), tb, 0, stream>>>(sh_w3, sh3T, 1024, 1024);
  transpose_conv<<<dim3(32, 32, 8), tb, 0, stream>>>(re_w1, re1T, 1024, 1024);
  transpose_conv<<<dim3(32, 32, 8), tb, 0, stream>>>(re_w2, re2T, 1024, 1024);
  transpose_conv<<<dim3(32, 32, 8), tb, 0, stream>>>(re_w3, re3T, 1024, 1024);

  // xn = rmsnorm(x, ln1_w)
  rmsnorm_kernel<1024><<<Tt, 256, 0, stream>>>(x, ln1_w, xn);

  // q = xn @ q_w ; latent_pre = xn @ kvd_w
  gemm_bt<0,0><<<dim3(8, 32), 256, 0, stream>>>(xn, qT, qact, nullptr, nullptr,
      Tt, 1024, 1024, nullptr, nullptr, nullptr, nullptr, nullptr);
  gemm_bt<0,2><<<dim3(2, 32), 256, 0, stream>>>(xn, kvdT, latpre, nullptr, nullptr,
      Tt, 256, 1024, nullptr, nullptr, nullptr, nullptr, nullptr);
  rmsnorm_kernel<256><<<Tt, 256, 0, stream>>>(latpre, kvn_w, lat);
  // kv = latent @ kvu_w
  gemm_bt<0,0><<<dim3(16, 32), 256, 0, stream>>>(lat, kvuT, kvbuf, nullptr, nullptr,
      Tt, 2048, 256, nullptr, nullptr, nullptr, nullptr, nullptr);
  // V^T precompute + attention
  vt_kernel<<<dim3(32, 16, 2), 256, 0, stream>>>(kvbuf, vtb);
  attn_kernel<<<dim3(32, 16, 2), 256, 0, stream>>>(qact, kvbuf, vtb, attnb);
  // h = x + attn_out @ o_w
  gemm_bt<0,1><<<dim3(8, 32), 256, 0, stream>>>(attnb, oT, hbuf, x, nullptr,
      Tt, 1024, 1024, nullptr, nullptr, nullptr, nullptr, nullptr);
  // hn = rmsnorm(h, ln2_w)
  rmsnorm_kernel<1024><<<Tt, 256, 0, stream>>>(hbuf, ln2_w, xn);
  // router (fp32 from h), probs -> d_out tail
  router_kernel<<<Tt, 256, 0, stream>>>(hbuf, ln2_w, gate_w, out + (size_t)Tt * Dd,
                                        topi, topw, counts);
  scan_kernel<<<1, 64, 0, stream>>>(counts, offs);
  bucket_kernel<<<16, 256, 0, stream>>>(topi, topw, offs, cur, entries, ewt);

  // shared expert
  gemm_bt<0,0><<<dim3(8, 32), 256, 0, stream>>>(xn, sh3T, qact, nullptr, nullptr,
      Tt, 1024, 1024, nullptr, nullptr, nullptr, nullptr, nullptr);
  gemm_bt<0,3><<<dim3(8, 32), 256, 0, stream>>>(xn, sh1T, attnb, nullptr, qact,
      Tt, 1024, 1024, nullptr, nullptr, nullptr, nullptr, nullptr);
  gemm_bt<0,1><<<dim3(8, 32), 256, 0, stream>>>(attnb, sh2T, out, hbuf, nullptr,
      Tt, 1024, 1024, nullptr, nullptr, nullptr, nullptr, nullptr);

  // routed experts (gathered)
  gemm_bt<1,0><<<dim3(8, 32, 8), 256, 0, stream>>>(xn, re3T, r3, nullptr, nullptr,
      Tt, 1024, 1024, entries, nullptr, counts, offs, nullptr);
  gemm_bt<1,3><<<dim3(8, 32, 8), 256, 0, stream>>>(xn, re1T, kvbuf, nullptr, r3,
      Tt, 1024, 1024, entries, nullptr, counts, offs, nullptr);
  gemm_bt<2,4><<<dim3(8, 32, 8), 256, 0, stream>>>(kvbuf, re2T, nullptr, nullptr, nullptr,
      Tt, 1024, 1024, entries, ewt, counts, offs, out);
}

// Round 5
// 608.588 us; speedup vs baseline: 1.5594x; 1.3811x over previous
//
#include <hip/hip_runtime.h>
#include <hip/hip_bf16.h>
#include <cstdint>
#include <cstddef>

typedef unsigned short u16;
typedef unsigned int u32;
typedef __attribute__((ext_vector_type(8))) short bf16x8;
typedef __attribute__((ext_vector_type(4))) float f32x4;

static constexpr int Bb = 2, Ll = 2048, Dd = 1024, Hh = 16, Rr = 256, Ee = 8, Ff = 1024;
static constexpr int Tt = Bb * Ll;   // 4096 tokens

__device__ __forceinline__ u16 f2bf(float f){
  union { float f; u32 u; } v; v.f = f;
  u32 u = v.u;
  u32 r = u + 0x7FFFu + ((u >> 16) & 1u);
  return (u16)(r >> 16);
}
__device__ __forceinline__ float bf2f(u16 b){
  union { u32 u; float f; } v; v.u = ((u32)b) << 16; return v.f;
}

// async global->LDS, 16B per lane. LDS dest must be wave-uniform base + lane*16.
// NEVER issue with divergent exec.
#define GLDS(gp, lp) __builtin_amdgcn_global_load_lds( \
    (const __attribute__((address_space(1))) unsigned int*)(gp), \
    (__attribute__((address_space(3))) unsigned int*)(lp), 16, 0, 0)

// ---- transpose + fp32->bf16: src[K,N] (expert z) -> dst rows [z*SN + dstOff + n][K] ----
__global__ void transpose_conv(const float* __restrict__ src, u16* __restrict__ dst,
                               int K, int N, int SN, int dstOff){
  __shared__ float tile[32][33];
  const float* s = src + (size_t)blockIdx.z * K * N;
  int bx = blockIdx.x * 32;   // n
  int by = blockIdx.y * 32;   // k
  int tx = threadIdx.x, ty = threadIdx.y;
  #pragma unroll
  for (int i = ty; i < 32; i += 8) tile[i][tx] = s[(size_t)(by + i) * N + bx + tx];
  __syncthreads();
  size_t rowbase = (size_t)blockIdx.z * SN + dstOff + bx;
  #pragma unroll
  for (int i = ty; i < 32; i += 8) dst[(rowbase + i) * K + by + tx] = f2bf(tile[tx][i]);
}

// ---- rmsnorm: fp32 in -> bf16 out ----
template<int DIM>
__global__ void rmsnorm_kernel(const float* __restrict__ x, const float* __restrict__ w,
                               u16* __restrict__ out){
  int t = blockIdx.x;
  const float* xr = x + (size_t)t * DIM;
  u16* orow = out + (size_t)t * DIM;
  int tid = threadIdx.x;
  constexpr int NT = 256;
  constexpr int PER = DIM / NT > 0 ? DIM / NT : 1;
  float vals[PER];
  float ss = 0.f;
  #pragma unroll
  for (int i = 0; i < PER; i++){
    int d = tid + i * NT;
    float v = (d < DIM) ? xr[d] : 0.f;
    vals[i] = v; ss += v * v;
  }
  __shared__ float red[4];
  for (int m = 32; m; m >>= 1) ss += __shfl_xor(ss, m, 64);
  if ((tid & 63) == 0) red[tid >> 6] = ss;
  __syncthreads();
  float tot = red[0] + red[1] + red[2] + red[3];
  float rn = rsqrtf(tot / DIM + 1e-6f);
  #pragma unroll
  for (int i = 0; i < PER; i++){
    int d = tid + i * NT;
    if (d < DIM) orow[d] = f2bf(vals[i] * rn * w[d]);
  }
}

// ---- router: fp32 rmsnorm(h)@gate, softmax, top2 (NO global atomics) ----
__global__ void router_kernel(const float* __restrict__ h, const float* __restrict__ ln2w,
                              const float* __restrict__ gate,
                              float* __restrict__ probs_out,
                              int* __restrict__ topi, float* __restrict__ topw){
  int t = blockIdx.x; int tid = threadIdx.x;
  const float* hr = h + (size_t)t * Dd;
  float v[4]; float ss = 0.f;
  #pragma unroll
  for (int i = 0; i < 4; i++){ float x = hr[tid + i * 256]; v[i] = x; ss += x * x; }
  __shared__ float red[4];
  for (int m = 32; m; m >>= 1) ss += __shfl_xor(ss, m, 64);
  if ((tid & 63) == 0) red[tid >> 6] = ss;
  __syncthreads();
  float rn = rsqrtf((red[0] + red[1] + red[2] + red[3]) / Dd + 1e-6f);
  float p[8];
  #pragma unroll
  for (int e = 0; e < 8; e++) p[e] = 0.f;
  #pragma unroll
  for (int i = 0; i < 4; i++){
    int d = tid + i * 256;
    float hv = v[i] * rn * ln2w[d];
    const float* g = gate + (size_t)d * 8;
    #pragma unroll
    for (int e = 0; e < 8; e++) p[e] += hv * g[e];
  }
  #pragma unroll
  for (int e = 0; e < 8; e++){
    float x = p[e];
    for (int m = 32; m; m >>= 1) x += __shfl_xor(x, m, 64);
    p[e] = x;
  }
  __shared__ float pe[4][8];
  if ((tid & 63) == 0){ for (int e = 0; e < 8; e++) pe[tid >> 6][e] = p[e]; }
  __syncthreads();
  if (tid == 0){
    float lg[8];
    for (int e = 0; e < 8; e++) lg[e] = pe[0][e] + pe[1][e] + pe[2][e] + pe[3][e];
    float mx = lg[0];
    for (int e = 1; e < 8; e++) mx = fmaxf(mx, lg[e]);
    float pr[8]; float s = 0.f;
    for (int e = 0; e < 8; e++){ pr[e] = __expf(lg[e] - mx); s += pr[e]; }
    float inv = 1.f / s;
    for (int e = 0; e < 8; e++) probs_out[(size_t)t * 8 + e] = pr[e] * inv;
    int i0 = 0;
    for (int e = 1; e < 8; e++) if (pr[e] > pr[i0]) i0 = e;
    int i1 = -1;
    for (int e = 0; e < 8; e++){ if (e == i0) continue; if (i1 < 0 || pr[e] > pr[i1]) i1 = e; }
    float w0 = pr[i0], w1 = pr[i1]; float wn = 1.f / (w0 + w1);
    topi[t * 2] = i0; topi[t * 2 + 1] = i1;
    topw[t * 2] = w0 * wn; topw[t * 2 + 1] = w1 * wn;
  }
}

// ---- histogram of topi -> counts (LDS-aggregated) ----
__global__ void hist_kernel(const int* __restrict__ topi, int* __restrict__ counts){
  __shared__ int h[8];
  int tid = threadIdx.x;
  if (tid < 8) h[tid] = 0;
  __syncthreads();
  int base = blockIdx.x * 512;
  for (int i = tid; i < 512; i += 256) atomicAdd(&h[topi[base + i]], 1);
  __syncthreads();
  if (tid < 8) atomicAdd(&counts[tid], h[tid]);
}

__global__ void scan_kernel(const int* __restrict__ counts, int* __restrict__ offs){
  if (threadIdx.x == 0 && blockIdx.x == 0){
    int c = 0;
    for (int e = 0; e < 8; e++){ offs[e] = c; c += counts[e]; }
  }
}

// ---- bucket: per-block LDS histogram + chunk reservation ----
__global__ void bucket_kernel(const int* __restrict__ topi, const float* __restrict__ topw,
                              const int* __restrict__ offs, int* __restrict__ cur,
                              int* __restrict__ entries, float* __restrict__ ew){
  __shared__ int lh[8], lbase[8], lcur[8];
  int tid = threadIdx.x;
  if (tid < 8) lh[tid] = 0;
  __syncthreads();
  int t = blockIdx.x * 256 + tid;
  int e0 = topi[t * 2], e1 = topi[t * 2 + 1];
  atomicAdd(&lh[e0], 1); atomicAdd(&lh[e1], 1);
  __syncthreads();
  if (tid < 8){ lbase[tid] = atomicAdd(&cur[tid], lh[tid]); lcur[tid] = 0; }
  __syncthreads();
  int p0 = atomicAdd(&lcur[e0], 1);
  int pos0 = offs[e0] + lbase[e0] + p0;
  entries[pos0] = t; ew[pos0] = topw[t * 2];
  int p1 = atomicAdd(&lcur[e1], 1);
  int pos1 = offs[e1] + lbase[e1] + p1;
  entries[pos1] = t; ew[pos1] = topw[t * 2 + 1];
}

// ---- SwiGLU in-place on [rows,2048] bf16: col f = silu(col f) * col (1024+f) ----
__global__ void swiglu_kernel(u16* __restrict__ buf, int rows){
  int idx = blockIdx.x * 256 + threadIdx.x;
  int t = idx >> 7, f = (idx & 127) * 8;
  if (t >= rows) return;
  u16* p = buf + (size_t)t * 2048 + f;
  bf16x8 a = *(const bf16x8*)p;
  bf16x8 b = *(const bf16x8*)(p + 1024);
  bf16x8 o;
  #pragma unroll
  for (int j = 0; j < 8; j++){
    float av = bf2f(((const u16*)&a)[j]);
    float bv = bf2f(((const u16*)&b)[j]);
    float s = av / (1.f + __expf(-av));
    ((u16*)&o)[j] = f2bf(s * bv);
  }
  *(bf16x8*)p = o;
}

// ---- bf16 GEMM: C[M,N] = A[M,K] @ Bt[N,K]^T ; m97 structure, tile TM x 128, BK=32 ----
// ROWMODE: 0 dense; 1 gather rows via entries; 2 dense-in-entry-space (A row = off+r)
// MODE: 0 bf16 C; 1 f32 C = acc + res; 4 atomicAdd(out[token], w*acc);
//       5 split: col<1024 -> bf16 C (ld 1024); col>=1024 -> fp32 outAt[rr*256+(col-1024)]
template<int TM, int ROWMODE, int MODE>
__launch_bounds__(256)
__global__ void gemm_bt(const u16* __restrict__ A, const u16* __restrict__ Bt,
                        void* __restrict__ C, const float* __restrict__ res,
                        int M, int N, int K, int lda, int ldc,
                        const int* __restrict__ entries, const float* __restrict__ ew,
                        const int* __restrict__ counts, const int* __restrict__ offs,
                        float* __restrict__ outAt){
  constexpr int MTC = TM / 32;       // m-frags per wave
  __shared__ __align__(16) u16 As[TM * 32];
  __shared__ __align__(16) u16 Bs[128 * 32];
  __shared__ int els[TM];
  __shared__ float ewl[TM];

  int e = (ROWMODE ? blockIdx.z : 0);
  const u16* Bte = Bt + (size_t)e * N * K;
  int cnt, off;
  if (ROWMODE == 0){ cnt = M; off = 0; }
  else { cnt = counts[e]; off = offs[e]; }
  int rt = blockIdx.y * TM;
  if (rt >= cnt) return;
  int cb = blockIdx.x * 128;
  int tid = threadIdx.x;

  if (ROWMODE >= 1){
    if (tid < TM){
      int r = rt + tid;
      els[tid] = (r < cnt) ? entries[off + r] : 0;   // pad -> token 0 (valid addr)
      ewl[tid] = (MODE == 4 && r < cnt) ? ew[off + r] : 0.f;
    }
    __syncthreads();
  }

  int sr = tid >> 2;            // 0..63
  int skc = (tid & 3) * 8;      // k-col offset (elements)
  int rr0 = rt + sr, rr1 = rt + sr + 64;
  size_t ar0 = 0, ar1 = 0;
  if (ROWMODE == 0){ ar0 = (size_t)rr0; ar1 = (size_t)rr1; }
  else if (ROWMODE == 1){ ar0 = (size_t)els[sr];
                          ar1 = (TM == 128) ? (size_t)els[sr + 64] : 0; }
  else {
    int c0 = rr0 < cnt ? rr0 : (cnt - 1);
    int c1 = rr1 < cnt ? rr1 : (cnt - 1);
    ar0 = (size_t)off + c0; ar1 = (size_t)off + c1;
  }
  const u16* pa0 = A + ar0 * lda + skc;
  const u16* pa1 = A + ar1 * lda + skc;
  const u16* pb0 = Bte + (size_t)(cb + sr) * K + skc;
  const u16* pb1 = Bte + (size_t)(cb + sr + 64) * K + skc;
  u16* lA0 = &As[tid * 8];
  u16* lA1 = &As[(TM == 128 ? 2048 : 0) + tid * 8];
  u16* lB0 = &Bs[tid * 8];
  u16* lB1 = &Bs[2048 + tid * 8];

  int w = tid >> 6, lane = tid & 63;
  int wm = w >> 1, wn = w & 1;
  int quad = lane >> 4, l16 = lane & 15;

  f32x4 acc[MTC][4];
  const f32x4 zf = {0.f, 0.f, 0.f, 0.f};
  #pragma unroll
  for (int i = 0; i < MTC; i++)
    #pragma unroll
    for (int j = 0; j < 4; j++) acc[i][j] = zf;

  for (int k0 = 0; k0 < K; k0 += 32){
    __syncthreads();
    GLDS(pa0 + k0, lA0);
    if (TM == 128) GLDS(pa1 + k0, lA1);
    GLDS(pb0 + k0, lB0);
    GLDS(pb1 + k0, lB1);
    __syncthreads();
    bf16x8 af[MTC], bfr[4];
    #pragma unroll
    for (int mt = 0; mt < MTC; mt++)
      af[mt] = *(const bf16x8*)&As[(wm * (TM / 2) + mt * 16 + l16) * 32 + quad * 8];
    #pragma unroll
    for (int nt = 0; nt < 4; nt++)
      bfr[nt] = *(const bf16x8*)&Bs[(wn * 64 + nt * 16 + l16) * 32 + quad * 8];
    #pragma unroll
    for (int mt = 0; mt < MTC; mt++)
      #pragma unroll
      for (int nt = 0; nt < 4; nt++)
        acc[mt][nt] = __builtin_amdgcn_mfma_f32_16x16x32_bf16(af[mt], bfr[nt], acc[mt][nt], 0, 0, 0);
  }

  #pragma unroll
  for (int mt = 0; mt < MTC; mt++){
    #pragma unroll
    for (int nt = 0; nt < 4; nt++){
      #pragma unroll
      for (int r = 0; r < 4; r++){
        int row = wm * (TM / 2) + mt * 16 + quad * 4 + r;
        int col = cb + wn * 64 + nt * 16 + l16;
        int rr = rt + row;
        if (rr >= cnt) continue;
        float v = acc[mt][nt][r];
        if (MODE == 0){
          size_t ci = (size_t)((ROWMODE == 1) ? (off + rr) : rr) * ldc + col;
          ((u16*)C)[ci] = f2bf(v);
        } else if (MODE == 1){
          size_t ci = (size_t)rr * ldc + col;
          ((float*)C)[ci] = v + res[ci];
        } else if (MODE == 5){
          if (col < 1024) ((u16*)C)[(size_t)rr * 1024 + col] = f2bf(v);
          else            outAt[(size_t)rr * 256 + (col - 1024)] = v;   // fp32 latent-pre
        } else {
          int tok = els[row];
          atomicAdd(&outAt[(size_t)tok * ldc + col], ewl[row] * v);
        }
      }
    }
  }
}

// ---- per-(b,h) V transpose: kv v-part [L,64] -> vt [64,L] ----
__global__ void vt_kernel(const u16* __restrict__ kv, u16* __restrict__ vt){
  __shared__ __align__(16) u16 t[64 * 72];
  int kt = blockIdx.x * 64, h = blockIdx.y, b = blockIdx.z;
  size_t bL = (size_t)b * Ll;
  int tid = threadIdx.x;
  int r = tid >> 2, c0 = (tid & 3) * 16;
  const u16* src = kv + (bL + kt + r) * 2048 + 1024 + h * 64 + c0;
  *(uint4*)&t[r * 72 + c0]     = *(const uint4*)(src);
  *(uint4*)&t[r * 72 + c0 + 8] = *(const uint4*)(src + 8);
  __syncthreads();
  int d = tid >> 2; int k0 = (tid & 3) * 16;
  u16 tmp[16];
  #pragma unroll
  for (int j = 0; j < 16; j++) tmp[j] = t[(k0 + j) * 72 + d];
  u16* dst = vt + ((size_t)(b * Hh + h) * 64 + d) * (size_t)Ll + kt + k0;
  *(uint4*)dst       = *(const uint4*)&tmp[0];
  *(uint4*)(dst + 8) = *(const uint4*)&tmp[8];
}

// ---- flash attention via S^T = K Q^T, O^T = V^T P ----
__launch_bounds__(256)
__global__ void attn_kernel(const u16* __restrict__ q, const u16* __restrict__ kv,
                            const u16* __restrict__ vt, u16* __restrict__ out){
  constexpr int LD = 72;
  __shared__ __align__(16) u16 Ks[64 * LD];
  __shared__ __align__(16) u16 Vs[64 * LD];
  __shared__ __align__(16) u16 Ps[64 * LD];
  int q0 = blockIdx.x * 64, h = blockIdx.y, b = blockIdx.z;
  size_t bL = (size_t)b * Ll;
  int tid = threadIdx.x, w = tid >> 6, lane = tid & 63, quad = lane >> 4, l16 = lane & 15;
  int qrow = q0 + w * 16 + l16;

  bf16x8 qf[2];
  #pragma unroll
  for (int ks = 0; ks < 2; ks++)
    qf[ks] = *(const bf16x8*)(q + (bL + qrow) * 1024 + h * 64 + ks * 32 + quad * 8);

  f32x4 oacc[4];
  const f32x4 zf = {0.f, 0.f, 0.f, 0.f};
  #pragma unroll
  for (int dt = 0; dt < 4; dt++) oacc[dt] = zf;
  float mprev = -1e30f, lsum = 0.f;

  int sr = tid >> 2, sc = (tid & 3) * 16;
  const u16* kbase = kv + (bL + sr) * 2048 + h * 64 + sc;
  const u16* vbase = vt + ((size_t)(b * Hh + h) * 64 + sr) * (size_t)Ll + sc;

  for (int kt = 0; kt <= q0; kt += 64){
    __syncthreads();
    {
      const u16* kp = kbase + (size_t)kt * 2048;
      *(uint4*)&Ks[sr * LD + sc]     = *(const uint4*)(kp);
      *(uint4*)&Ks[sr * LD + sc + 8] = *(const uint4*)(kp + 8);
      const u16* vp = vbase + kt;
      *(uint4*)&Vs[sr * LD + sc]     = *(const uint4*)(vp);
      *(uint4*)&Vs[sr * LD + sc + 8] = *(const uint4*)(vp + 8);
    }
    __syncthreads();

    f32x4 sacc[4];
    #pragma unroll
    for (int mt = 0; mt < 4; mt++) sacc[mt] = zf;
    #pragma unroll
    for (int ks = 0; ks < 2; ks++){
      #pragma unroll
      for (int mt = 0; mt < 4; mt++){
        bf16x8 kf = *(const bf16x8*)&Ks[(mt * 16 + l16) * LD + ks * 32 + quad * 8];
        sacc[mt] = __builtin_amdgcn_mfma_f32_16x16x32_bf16(kf, qf[ks], sacc[mt], 0, 0, 0);
      }
    }
    bool diag = (kt == q0);
    int lq = w * 16 + l16;
    float sv[16]; float mx = -1e30f;
    #pragma unroll
    for (int mt = 0; mt < 4; mt++){
      #pragma unroll
      for (int r = 0; r < 4; r++){
        float s = sacc[mt][r] * 0.125f;
        if (diag && (mt * 16 + quad * 4 + r > lq)) s = -1e30f;
        sv[mt * 4 + r] = s;
        mx = fmaxf(mx, s);
      }
    }
    mx = fmaxf(mx, __shfl_xor(mx, 16, 64));
    mx = fmaxf(mx, __shfl_xor(mx, 32, 64));
    float mnew = fmaxf(mprev, mx);
    float alpha = __expf(mprev - mnew);
    mprev = mnew;
    float rs = 0.f;
    #pragma unroll
    for (int mt = 0; mt < 4; mt++){
      ushort4 pk;
      float p0 = __expf(sv[mt * 4 + 0] - mnew);
      float p1 = __expf(sv[mt * 4 + 1] - mnew);
      float p2 = __expf(sv[mt * 4 + 2] - mnew);
      float p3 = __expf(sv[mt * 4 + 3] - mnew);
      rs += p0 + p1 + p2 + p3;
      pk.x = f2bf(p0); pk.y = f2bf(p1); pk.z = f2bf(p2); pk.w = f2bf(p3);
      *(ushort4*)&Ps[(w * 16 + l16) * LD + mt * 16 + quad * 4] = pk;
    }
    rs += __shfl_xor(rs, 16, 64);
    rs += __shfl_xor(rs, 32, 64);
    lsum = lsum * alpha + rs;
    #pragma unroll
    for (int dt = 0; dt < 4; dt++) oacc[dt] *= alpha;

    #pragma unroll
    for (int ks = 0; ks < 2; ks++){
      bf16x8 pf = *(const bf16x8*)&Ps[(w * 16 + l16) * LD + ks * 32 + quad * 8];
      #pragma unroll
      for (int dt = 0; dt < 4; dt++){
        bf16x8 vf = *(const bf16x8*)&Vs[(dt * 16 + l16) * LD + ks * 32 + quad * 8];
        oacc[dt] = __builtin_amdgcn_mfma_f32_16x16x32_bf16(vf, pf, oacc[dt], 0, 0, 0);
      }
    }
  }

  float inv = 1.f / lsum;
  #pragma unroll
  for (int dt = 0; dt < 4; dt++){
    ushort4 ov;
    ov.x = f2bf(oacc[dt][0] * inv);
    ov.y = f2bf(oacc[dt][1] * inv);
    ov.z = f2bf(oacc[dt][2] * inv);
    ov.w = f2bf(oacc[dt][3] * inv);
    *(ushort4*)(out + (bL + qrow) * 1024 + h * 64 + dt * 16 + quad * 4) = ov;
  }
}

// ---------------- host launch ----------------
extern "C" void kernel_launch(void* const* d_in, const int* in_sizes, int n_in,
                              void* d_out, int out_size, void* d_ws, size_t ws_size,
                              hipStream_t stream){
  const float* x     = (const float*)d_in[0];
  const float* ln1_w = (const float*)d_in[1];
  const float* q_w   = (const float*)d_in[2];
  const float* kvd_w = (const float*)d_in[3];
  const float* kvn_w = (const float*)d_in[4];
  const float* kvu_w = (const float*)d_in[5];
  const float* o_w   = (const float*)d_in[6];
  const float* ln2_w = (const float*)d_in[7];
  const float* gate_w= (const float*)d_in[8];
  const float* sh_w1 = (const float*)d_in[9];
  const float* sh_w2 = (const float*)d_in[10];
  const float* sh_w3 = (const float*)d_in[11];
  const float* re_w1 = (const float*)d_in[12];
  const float* re_w2 = (const float*)d_in[13];
  const float* re_w3 = (const float*)d_in[14];
  float* out = (float*)d_out;

  char* wp = (char*)d_ws;
  auto alloc = [&](size_t bytes)->char*{
    char* p = wp; wp += (bytes + 255) & ~(size_t)255; return p;
  };
  u16* qkvdT = (u16*)alloc((size_t)1280 * 1024 * 2);            // q rows 0..1023, kvd 1024..1279
  u16* kvuT  = (u16*)alloc((size_t)2048 * 256 * 2);
  u16* oT    = (u16*)alloc((size_t)1024 * 1024 * 2);
  u16* sh13T = (u16*)alloc((size_t)2048 * 1024 * 2);            // w1 rows 0..1023, w3 1024..2047
  u16* sh2T  = (u16*)alloc((size_t)1024 * 1024 * 2);
  u16* re13T = (u16*)alloc((size_t)8 * 2048 * 1024 * 2);
  u16* re2T  = (u16*)alloc((size_t)8 * 1024 * 1024 * 2);
  u16* xn    = (u16*)alloc((size_t)Tt * 1024 * 2);              // xn, later hn
  u16* qbuf  = (u16*)alloc((size_t)Tt * 1024 * 2);
  float* latpre = (float*)alloc((size_t)Tt * 256 * 4);          // fp32 (routing-critical)
  u16* lat   = (u16*)alloc((size_t)Tt * 256 * 2);
  u16* kvbuf = (u16*)alloc((size_t)Tt * 2048 * 2);              // kv, later shared h13
  u16* attnb = (u16*)alloc((size_t)Tt * 1024 * 2);
  float* hbuf = (float*)alloc((size_t)Tt * 1024 * 4);
  u16* vtb   = (u16*)alloc((size_t)Bb * Hh * 64 * Ll * 2);
  u16* h13r  = (u16*)alloc((size_t)Tt * 2 * 2048 * 2);          // routed h13
  int* counts = (int*)alloc(32);
  int* cur    = (int*)alloc(32);
  int* offs   = (int*)alloc(32);
  int* topi   = (int*)alloc((size_t)Tt * 2 * 4);
  float* topw = (float*)alloc((size_t)Tt * 2 * 4);
  int* entries= (int*)alloc((size_t)Tt * 2 * 4);
  float* ewt  = (float*)alloc((size_t)Tt * 2 * 4);
  (void)ws_size; (void)n_in; (void)in_sizes; (void)out_size;

  hipMemsetAsync(counts, 0, 32, stream);
  hipMemsetAsync(cur, 0, 32, stream);

  dim3 tb(32, 8);
  transpose_conv<<<dim3(32, 32, 1), tb, 0, stream>>>(q_w,   qkvdT, 1024, 1024, 1280, 0);
  transpose_conv<<<dim3(8,  32, 1), tb, 0, stream>>>(kvd_w, qkvdT, 1024, 256,  1280, 1024);
  transpose_conv<<<dim3(64, 8,  1), tb, 0, stream>>>(kvu_w, kvuT,  256,  2048, 2048, 0);
  transpose_conv<<<dim3(32, 32, 1), tb, 0, stream>>>(o_w,   oT,    1024, 1024, 1024, 0);
  transpose_conv<<<dim3(32, 32, 1), tb, 0, stream>>>(sh_w1, sh13T, 1024, 1024, 2048, 0);
  transpose_conv<<<dim3(32, 32, 1), tb, 0, stream>>>(sh_w3, sh13T, 1024, 1024, 2048, 1024);
  transpose_conv<<<dim3(32, 32, 1), tb, 0, stream>>>(sh_w2, sh2T,  1024, 1024, 1024, 0);
  transpose_conv<<<dim3(32, 32, 8), tb, 0, stream>>>(re_w1, re13T, 1024, 1024, 2048, 0);
  transpose_conv<<<dim3(32, 32, 8), tb, 0, stream>>>(re_w3, re13T, 1024, 1024, 2048, 1024);
  transpose_conv<<<dim3(32, 32, 8), tb, 0, stream>>>(re_w2, re2T,  1024, 1024, 1024, 0);

  // xn = rmsnorm(x, ln1_w)
  rmsnorm_kernel<1024><<<Tt, 256, 0, stream>>>(x, ln1_w, xn);

  // [q(bf16) | latent_pre(fp32)] = xn @ [q_w | kvd_w]  (MODE 5 split epilogue)
  gemm_bt<64,0,5><<<dim3(10, 64), 256, 0, stream>>>(xn, qkvdT, qbuf, nullptr,
      Tt, 1280, 1024, 1024, 1024, nullptr, nullptr, nullptr, nullptr, latpre);
  rmsnorm_kernel<256><<<Tt, 256, 0, stream>>>(latpre, kvn_w, lat);
  // kv = latent @ kvu_w
  gemm_bt<128,0,0><<<dim3(16, 32), 256, 0, stream>>>(lat, kvuT, kvbuf, nullptr,
      Tt, 2048, 256, 256, 2048, nullptr, nullptr, nullptr, nullptr, nullptr);
  // attention
  vt_kernel<<<dim3(32, 16, 2), 256, 0, stream>>>(kvbuf, vtb);
  attn_kernel<<<dim3(32, 16, 2), 256, 0, stream>>>(qbuf, kvbuf, vtb, attnb);
  // h = x + attn_out @ o_w
  gemm_bt<64,0,1><<<dim3(8, 64), 256, 0, stream>>>(attnb, oT, hbuf, x,
      Tt, 1024, 1024, 1024, 1024, nullptr, nullptr, nullptr, nullptr, nullptr);
  // hn = rmsnorm(h, ln2_w)
  rmsnorm_kernel<1024><<<Tt, 256, 0, stream>>>(hbuf, ln2_w, xn);
  // router + bucketing
  router_kernel<<<Tt, 256, 0, stream>>>(hbuf, ln2_w, gate_w, out + (size_t)Tt * Dd,
                                        topi, topw);
  hist_kernel<<<16, 256, 0, stream>>>(topi, counts);
  scan_kernel<<<1, 64, 0, stream>>>(counts, offs);
  bucket_kernel<<<16, 256, 0, stream>>>(topi, topw, offs, cur, entries, ewt);

  // shared expert: h13 = hn @ [w1|w3]; in-place swiglu; out = h + g @ w2
  gemm_bt<128,0,0><<<dim3(16, 32), 256, 0, stream>>>(xn, sh13T, kvbuf, nullptr,
      Tt, 2048, 1024, 1024, 2048, nullptr, nullptr, nullptr, nullptr, nullptr);
  swiglu_kernel<<<Tt / 2, 256, 0, stream>>>(kvbuf, Tt);
  gemm_bt<64,0,1><<<dim3(8, 64), 256, 0, stream>>>(kvbuf, sh2T, out, hbuf,
      Tt, 1024, 1024, 2048, 1024, nullptr, nullptr, nullptr, nullptr, nullptr);

  // routed experts: h13r = gather(hn) @ [w1|w3]e; swiglu; out += w * (g @ w2e)
  gemm_bt<128,1,0><<<dim3(16, 32, 8), 256, 0, stream>>>(xn, re13T, h13r, nullptr,
      Tt, 2048, 1024, 1024, 2048, entries, nullptr, counts, offs, nullptr);
  swiglu_kernel<<<Tt, 256, 0, stream>>>(h13r, 2 * Tt);
  gemm_bt<128,2,4><<<dim3(8, 32, 8), 256, 0, stream>>>(h13r, re2T, nullptr, nullptr,
      Tt, 1024, 1024, 2048, 1024, entries, ewt, counts, offs, out);
}

// Round 6
// 580.342 us; speedup vs baseline: 1.6353x; 1.0487x over previous
//
#include <hip/hip_runtime.h>
#include <hip/hip_bf16.h>
#include <cstdint>
#include <cstddef>

typedef unsigned short u16;
typedef unsigned int u32;
typedef __attribute__((ext_vector_type(8))) short bf16x8;
typedef __attribute__((ext_vector_type(4))) float f32x4;

static constexpr int Bb = 2, Ll = 2048, Dd = 1024, Hh = 16, Rr = 256, Ee = 8, Ff = 1024;
static constexpr int Tt = Bb * Ll;   // 4096 tokens

__device__ __forceinline__ u16 f2bf(float f){
  union { float f; u32 u; } v; v.f = f;
  u32 u = v.u;
  u32 r = u + 0x7FFFu + ((u >> 16) & 1u);
  return (u16)(r >> 16);
}
__device__ __forceinline__ float bf2f(u16 b){
  union { u32 u; float f; } v; v.u = ((u32)b) << 16; return v.f;
}

// async global->LDS, 16B per lane. LDS dest wave-uniform base + lane*16. Full exec only.
#define GLDS(gp, lp) __builtin_amdgcn_global_load_lds( \
    (const __attribute__((address_space(1))) unsigned int*)(gp), \
    (__attribute__((address_space(3))) unsigned int*)(lp), 16, 0, 0)

// ---- batched transpose+convert for the five 1024x1024 non-expert weights ----
__global__ void transpose5(const float* __restrict__ q_w, const float* __restrict__ o_w,
                           const float* __restrict__ w1, const float* __restrict__ w3,
                           const float* __restrict__ w2,
                           u16* __restrict__ qkvdT, u16* __restrict__ oT,
                           u16* __restrict__ sh13T, u16* __restrict__ sh2T){
  const float* s; u16* d; int off, str;
  switch (blockIdx.z){
    case 0: s = q_w; d = qkvdT; off = 0; str = 1; break;
    case 1: s = o_w; d = oT;    off = 0; str = 1; break;
    case 2: s = w1;  d = sh13T; off = 0; str = 2; break;   // interleaved w1|w3
    case 3: s = w3;  d = sh13T; off = 1; str = 2; break;
    default: s = w2; d = sh2T;  off = 0; str = 1; break;
  }
  __shared__ float tile[32][33];
  int bx = blockIdx.x * 32, by = blockIdx.y * 32;
  int tx = threadIdx.x, ty = threadIdx.y;
  #pragma unroll
  for (int i = ty; i < 32; i += 8) tile[i][tx] = s[(size_t)(by + i) * 1024 + bx + tx];
  __syncthreads();
  #pragma unroll
  for (int i = ty; i < 32; i += 8)
    d[(size_t)(off + (bx + i) * str) * 1024 + by + tx] = f2bf(tile[tx][i]);
}

// ---- batched transpose+convert for the 24 expert weights ----
__global__ void transposeEx(const float* __restrict__ re_w1, const float* __restrict__ re_w3,
                            const float* __restrict__ re_w2,
                            u16* __restrict__ re13T, u16* __restrict__ re2T){
  int z = blockIdx.z, which = z >> 3, e = z & 7;
  const float* s; u16* d; int off, str;
  size_t eo = (size_t)e * 1024 * 1024;
  if (which == 0){ s = re_w1 + eo; d = re13T + (size_t)e * 2048 * 1024; off = 0; str = 2; }
  else if (which == 1){ s = re_w3 + eo; d = re13T + (size_t)e * 2048 * 1024; off = 1; str = 2; }
  else { s = re_w2 + eo; d = re2T + (size_t)e * 1024 * 1024; off = 0; str = 1; }
  __shared__ float tile[32][33];
  int bx = blockIdx.x * 32, by = blockIdx.y * 32;
  int tx = threadIdx.x, ty = threadIdx.y;
  #pragma unroll
  for (int i = ty; i < 32; i += 8) tile[i][tx] = s[(size_t)(by + i) * 1024 + bx + tx];
  __syncthreads();
  #pragma unroll
  for (int i = ty; i < 32; i += 8)
    d[(size_t)(off + (bx + i) * str) * 1024 + by + tx] = f2bf(tile[tx][i]);
}

// ---- generic transpose (kvd: K=1024,N=256 ; kvu: K=256,N=2048) ----
__global__ void transpose_conv(const float* __restrict__ src, u16* __restrict__ dst,
                               int K, int N, int dstOff){
  __shared__ float tile[32][33];
  int bx = blockIdx.x * 32, by = blockIdx.y * 32;
  int tx = threadIdx.x, ty = threadIdx.y;
  #pragma unroll
  for (int i = ty; i < 32; i += 8) tile[i][tx] = src[(size_t)(by + i) * N + bx + tx];
  __syncthreads();
  #pragma unroll
  for (int i = ty; i < 32; i += 8)
    dst[(size_t)(dstOff + bx + i) * K + by + tx] = f2bf(tile[tx][i]);
}

// ---- rmsnorm: fp32 in -> bf16 out ----
template<int DIM>
__global__ void rmsnorm_kernel(const float* __restrict__ x, const float* __restrict__ w,
                               u16* __restrict__ out){
  int t = blockIdx.x;
  const float* xr = x + (size_t)t * DIM;
  u16* orow = out + (size_t)t * DIM;
  int tid = threadIdx.x;
  constexpr int NT = 256;
  constexpr int PER = DIM / NT > 0 ? DIM / NT : 1;
  float vals[PER];
  float ss = 0.f;
  #pragma unroll
  for (int i = 0; i < PER; i++){
    int d = tid + i * NT;
    float v = (d < DIM) ? xr[d] : 0.f;
    vals[i] = v; ss += v * v;
  }
  __shared__ float red[4];
  for (int m = 32; m; m >>= 1) ss += __shfl_xor(ss, m, 64);
  if ((tid & 63) == 0) red[tid >> 6] = ss;
  __syncthreads();
  float tot = red[0] + red[1] + red[2] + red[3];
  float rn = rsqrtf(tot / DIM + 1e-6f);
  #pragma unroll
  for (int i = 0; i < PER; i++){
    int d = tid + i * NT;
    if (d < DIM) orow[d] = f2bf(vals[i] * rn * w[d]);
  }
}

// ---- router: fp32 rmsnorm(h)@gate, softmax, top2; ALSO writes hn (bf16) ----
__global__ void router_kernel(const float* __restrict__ h, const float* __restrict__ ln2w,
                              const float* __restrict__ gate,
                              float* __restrict__ probs_out,
                              int* __restrict__ topi, float* __restrict__ topw,
                              u16* __restrict__ hn){
  int t = blockIdx.x; int tid = threadIdx.x;
  const float* hr = h + (size_t)t * Dd;
  float v[4]; float ss = 0.f;
  #pragma unroll
  for (int i = 0; i < 4; i++){ float x = hr[tid + i * 256]; v[i] = x; ss += x * x; }
  __shared__ float red[4];
  for (int m = 32; m; m >>= 1) ss += __shfl_xor(ss, m, 64);
  if ((tid & 63) == 0) red[tid >> 6] = ss;
  __syncthreads();
  float rn = rsqrtf((red[0] + red[1] + red[2] + red[3]) / Dd + 1e-6f);
  float p[8];
  #pragma unroll
  for (int e = 0; e < 8; e++) p[e] = 0.f;
  #pragma unroll
  for (int i = 0; i < 4; i++){
    int d = tid + i * 256;
    float hv = v[i] * rn * ln2w[d];
    hn[(size_t)t * Dd + d] = f2bf(hv);
    const float* g = gate + (size_t)d * 8;
    #pragma unroll
    for (int e = 0; e < 8; e++) p[e] += hv * g[e];
  }
  #pragma unroll
  for (int e = 0; e < 8; e++){
    float x = p[e];
    for (int m = 32; m; m >>= 1) x += __shfl_xor(x, m, 64);
    p[e] = x;
  }
  __shared__ float pe[4][8];
  if ((tid & 63) == 0){ for (int e = 0; e < 8; e++) pe[tid >> 6][e] = p[e]; }
  __syncthreads();
  if (tid == 0){
    float lg[8];
    for (int e = 0; e < 8; e++) lg[e] = pe[0][e] + pe[1][e] + pe[2][e] + pe[3][e];
    float mx = lg[0];
    for (int e = 1; e < 8; e++) mx = fmaxf(mx, lg[e]);
    float pr[8]; float s = 0.f;
    for (int e = 0; e < 8; e++){ pr[e] = __expf(lg[e] - mx); s += pr[e]; }
    float inv = 1.f / s;
    for (int e = 0; e < 8; e++) probs_out[(size_t)t * 8 + e] = pr[e] * inv;
    int i0 = 0;
    for (int e = 1; e < 8; e++) if (pr[e] > pr[i0]) i0 = e;
    int i1 = -1;
    for (int e = 0; e < 8; e++){ if (e == i0) continue; if (i1 < 0 || pr[e] > pr[i1]) i1 = e; }
    float w0 = pr[i0], w1 = pr[i1]; float wn = 1.f / (w0 + w1);
    topi[t * 2] = i0; topi[t * 2 + 1] = i1;
    topw[t * 2] = w0 * wn; topw[t * 2 + 1] = w1 * wn;
  }
}

// ---- histogram of topi -> counts (LDS-aggregated) ----
__global__ void hist_kernel(const int* __restrict__ topi, int* __restrict__ counts){
  __shared__ int h[8];
  int tid = threadIdx.x;
  if (tid < 8) h[tid] = 0;
  __syncthreads();
  int base = blockIdx.x * 512;
  for (int i = tid; i < 512; i += 256) atomicAdd(&h[topi[base + i]], 1);
  __syncthreads();
  if (tid < 8) atomicAdd(&counts[tid], h[tid]);
}

// ---- bucket: LDS histogram + chunk reservation; offsets computed from counts ----
__global__ void bucket_kernel(const int* __restrict__ topi, const float* __restrict__ topw,
                              const int* __restrict__ counts, int* __restrict__ cur,
                              int* __restrict__ entries, float* __restrict__ ew){
  __shared__ int lh[8], lbase[8], lcur[8], loffs[8];
  int tid = threadIdx.x;
  if (tid < 8) lh[tid] = 0;
  __syncthreads();
  int t = blockIdx.x * 256 + tid;
  int e0 = topi[t * 2], e1 = topi[t * 2 + 1];
  atomicAdd(&lh[e0], 1); atomicAdd(&lh[e1], 1);
  __syncthreads();
  if (tid == 0){
    int c = 0;
    for (int e = 0; e < 8; e++){ loffs[e] = c; c += counts[e]; }
  }
  if (tid < 8){ lbase[tid] = atomicAdd(&cur[tid], lh[tid]); lcur[tid] = 0; }
  __syncthreads();
  int p0 = atomicAdd(&lcur[e0], 1);
  int pos0 = loffs[e0] + lbase[e0] + p0;
  entries[pos0] = t; ew[pos0] = topw[t * 2];
  int p1 = atomicAdd(&lcur[e1], 1);
  int pos1 = loffs[e1] + lbase[e1] + p1;
  entries[pos1] = t; ew[pos1] = topw[t * 2 + 1];
}

// ---- bf16 GEMM: C[M,N] = A[M,K] @ Bt[N,K]^T ; m97 structure, tile TM x 128, BK=32 ----
// ROWMODE: 0 dense; 1 gather rows via entries; 2 dense-in-entry-space (A row = off+r)
// MODE: 0 bf16 C; 1 f32 C = acc + res; 4 atomicAdd(out[token], w*acc);
//       5 split: col<1024 -> bf16 C; col>=1024 -> fp32 outAt (latent-pre, routing-critical)
//       6 swiglu: interleaved even/odd cols = (h1,h3); write silu(h1)*h3 bf16 at col>>1
template<int TM, int ROWMODE, int MODE>
__launch_bounds__(256)
__global__ void gemm_bt(const u16* __restrict__ A, const u16* __restrict__ Bt,
                        void* __restrict__ C, const float* __restrict__ res,
                        int M, int N, int K, int lda, int ldc,
                        const int* __restrict__ entries, const float* __restrict__ ew,
                        const int* __restrict__ counts,
                        float* __restrict__ outAt){
  constexpr int MTC = TM / 32;
  __shared__ __align__(16) u16 As[TM * 32];
  __shared__ __align__(16) u16 Bs[128 * 32];
  __shared__ int els[TM];
  __shared__ float ewl[TM];

  int e = (ROWMODE ? blockIdx.z : 0);
  const u16* Bte = Bt + (size_t)e * N * K;
  int cnt, off;
  if (ROWMODE == 0){ cnt = M; off = 0; }
  else {
    cnt = counts[e];
    off = 0;
    for (int i = 0; i < e; i++) off += counts[i];
  }
  int rt = blockIdx.y * TM;
  if (rt >= cnt) return;
  int cb = blockIdx.x * 128;
  int tid = threadIdx.x;

  if (ROWMODE >= 1){
    if (tid < TM){
      int r = rt + tid;
      els[tid] = (r < cnt) ? entries[off + r] : 0;
      ewl[tid] = (MODE == 4 && r < cnt) ? ew[off + r] : 0.f;
    }
    __syncthreads();
  }

  int sr = tid >> 2;
  int skc = (tid & 3) * 8;
  int rr0 = rt + sr, rr1 = rt + sr + 64;
  size_t ar0 = 0, ar1 = 0;
  if (ROWMODE == 0){ ar0 = (size_t)rr0; ar1 = (size_t)rr1; }
  else if (ROWMODE == 1){ ar0 = (size_t)els[sr];
                          ar1 = (TM == 128) ? (size_t)els[sr + 64] : 0; }
  else {
    int c0 = rr0 < cnt ? rr0 : (cnt - 1);
    int c1 = rr1 < cnt ? rr1 : (cnt - 1);
    ar0 = (size_t)off + c0; ar1 = (size_t)off + c1;
  }
  const u16* pa0 = A + ar0 * lda + skc;
  const u16* pa1 = A + ar1 * lda + skc;
  const u16* pb0 = Bte + (size_t)(cb + sr) * K + skc;
  const u16* pb1 = Bte + (size_t)(cb + sr + 64) * K + skc;
  u16* lA0 = &As[tid * 8];
  u16* lA1 = &As[(TM == 128 ? 2048 : 0) + tid * 8];
  u16* lB0 = &Bs[tid * 8];
  u16* lB1 = &Bs[2048 + tid * 8];

  int w = tid >> 6, lane = tid & 63;
  int wm = w >> 1, wn = w & 1;
  int quad = lane >> 4, l16 = lane & 15;

  f32x4 acc[MTC][4];
  const f32x4 zf = {0.f, 0.f, 0.f, 0.f};
  #pragma unroll
  for (int i = 0; i < MTC; i++)
    #pragma unroll
    for (int j = 0; j < 4; j++) acc[i][j] = zf;

  for (int k0 = 0; k0 < K; k0 += 32){
    __syncthreads();
    GLDS(pa0 + k0, lA0);
    if (TM == 128) GLDS(pa1 + k0, lA1);
    GLDS(pb0 + k0, lB0);
    GLDS(pb1 + k0, lB1);
    __syncthreads();
    bf16x8 af[MTC], bfr[4];
    #pragma unroll
    for (int mt = 0; mt < MTC; mt++)
      af[mt] = *(const bf16x8*)&As[(wm * (TM / 2) + mt * 16 + l16) * 32 + quad * 8];
    #pragma unroll
    for (int nt = 0; nt < 4; nt++)
      bfr[nt] = *(const bf16x8*)&Bs[(wn * 64 + nt * 16 + l16) * 32 + quad * 8];
    #pragma unroll
    for (int mt = 0; mt < MTC; mt++)
      #pragma unroll
      for (int nt = 0; nt < 4; nt++)
        acc[mt][nt] = __builtin_amdgcn_mfma_f32_16x16x32_bf16(af[mt], bfr[nt], acc[mt][nt], 0, 0, 0);
  }

  #pragma unroll
  for (int mt = 0; mt < MTC; mt++){
    #pragma unroll
    for (int nt = 0; nt < 4; nt++){
      #pragma unroll
      for (int r = 0; r < 4; r++){
        int row = wm * (TM / 2) + mt * 16 + quad * 4 + r;
        int col = cb + wn * 64 + nt * 16 + l16;
        int rr = rt + row;
        float v = acc[mt][nt][r];
        if (MODE == 6){
          float pv = __shfl_xor(v, 1, 64);      // partner col (all lanes execute)
          if (rr < cnt && (l16 & 1) == 0){
            float sl = v / (1.f + __expf(-v));
            size_t crow = (size_t)((ROWMODE == 1) ? (off + rr) : rr);
            ((u16*)C)[crow * ldc + (col >> 1)] = f2bf(sl * pv);
          }
          continue;
        }
        if (rr >= cnt) continue;
        if (MODE == 0){
          size_t ci = (size_t)((ROWMODE == 1) ? (off + rr) : rr) * ldc + col;
          ((u16*)C)[ci] = f2bf(v);
        } else if (MODE == 1){
          size_t ci = (size_t)rr * ldc + col;
          ((float*)C)[ci] = v + res[ci];
        } else if (MODE == 5){
          if (col < 1024) ((u16*)C)[(size_t)rr * 1024 + col] = f2bf(v);
          else            outAt[(size_t)rr * 256 + (col - 1024)] = v;
        } else {
          int tok = els[row];
          atomicAdd(&outAt[(size_t)tok * ldc + col], ewl[row] * v);
        }
      }
    }
  }
}

// ---- per-(b,h) V transpose: kv v-part [L,64] -> vt [64,L] ----
__global__ void vt_kernel(const u16* __restrict__ kv, u16* __restrict__ vt){
  __shared__ __align__(16) u16 t[64 * 72];
  int kt = blockIdx.x * 64, h = blockIdx.y, b = blockIdx.z;
  size_t bL = (size_t)b * Ll;
  int tid = threadIdx.x;
  int r = tid >> 2, c0 = (tid & 3) * 16;
  const u16* src = kv + (bL + kt + r) * 2048 + 1024 + h * 64 + c0;
  *(uint4*)&t[r * 72 + c0]     = *(const uint4*)(src);
  *(uint4*)&t[r * 72 + c0 + 8] = *(const uint4*)(src + 8);
  __syncthreads();
  int d = tid >> 2; int k0 = (tid & 3) * 16;
  u16 tmp[16];
  #pragma unroll
  for (int j = 0; j < 16; j++) tmp[j] = t[(k0 + j) * 72 + d];
  u16* dst = vt + ((size_t)(b * Hh + h) * 64 + d) * (size_t)Ll + kt + k0;
  *(uint4*)dst       = *(const uint4*)&tmp[0];
  *(uint4*)(dst + 8) = *(const uint4*)&tmp[8];
}

// ---- flash attention, S^T = K Q^T / O^T = V^T P; work-balanced: block x does
// q-bands {x, 31-x} (uniform 33 K-tiles/block). exp2-domain softmax. ----
__launch_bounds__(256)
__global__ void attn_kernel(const u16* __restrict__ q, const u16* __restrict__ kv,
                            const u16* __restrict__ vt, u16* __restrict__ out){
  constexpr int LD = 72;
  const float CS = 0.18033688011112042f;   // 0.125 * log2(e)
  __shared__ __align__(16) u16 Ks[64 * LD];
  __shared__ __align__(16) u16 Vs[64 * LD];
  __shared__ __align__(16) u16 Ps[64 * LD];
  int h = blockIdx.y, b = blockIdx.z;
  size_t bL = (size_t)b * Ll;
  int tid = threadIdx.x, w = tid >> 6, lane = tid & 63, quad = lane >> 4, l16 = lane & 15;
  int sr = tid >> 2, sc = (tid & 3) * 16;
  const u16* kbase = kv + (bL + sr) * 2048 + h * 64 + sc;
  const u16* vbase = vt + ((size_t)(b * Hh + h) * 64 + sr) * (size_t)Ll + sc;
  const f32x4 zf = {0.f, 0.f, 0.f, 0.f};

  #pragma unroll
  for (int pass = 0; pass < 2; pass++){
    int q0 = (pass ? (31 - (int)blockIdx.x) : (int)blockIdx.x) * 64;
    int qrow = q0 + w * 16 + l16;

    bf16x8 qf[2];
    #pragma unroll
    for (int ks = 0; ks < 2; ks++)
      qf[ks] = *(const bf16x8*)(q + (bL + qrow) * 1024 + h * 64 + ks * 32 + quad * 8);

    f32x4 oacc[4];
    #pragma unroll
    for (int dt = 0; dt < 4; dt++) oacc[dt] = zf;
    float mprev = -1e30f, lsum = 0.f;

    for (int kt = 0; kt <= q0; kt += 64){
      __syncthreads();
      {
        const u16* kp = kbase + (size_t)kt * 2048;
        *(uint4*)&Ks[sr * LD + sc]     = *(const uint4*)(kp);
        *(uint4*)&Ks[sr * LD + sc + 8] = *(const uint4*)(kp + 8);
        const u16* vp = vbase + kt;
        *(uint4*)&Vs[sr * LD + sc]     = *(const uint4*)(vp);
        *(uint4*)&Vs[sr * LD + sc + 8] = *(const uint4*)(vp + 8);
      }
      __syncthreads();

      f32x4 sacc[4];
      #pragma unroll
      for (int mt = 0; mt < 4; mt++) sacc[mt] = zf;
      #pragma unroll
      for (int ks = 0; ks < 2; ks++){
        #pragma unroll
        for (int mt = 0; mt < 4; mt++){
          bf16x8 kf = *(const bf16x8*)&Ks[(mt * 16 + l16) * LD + ks * 32 + quad * 8];
          sacc[mt] = __builtin_amdgcn_mfma_f32_16x16x32_bf16(kf, qf[ks], sacc[mt], 0, 0, 0);
        }
      }
      bool diag = (kt == q0);
      int lq = w * 16 + l16;
      float sv[16]; float mx = -1e30f;
      #pragma unroll
      for (int mt = 0; mt < 4; mt++){
        #pragma unroll
        for (int r = 0; r < 4; r++){
          float s = sacc[mt][r] * CS;            // log2-domain score
          if (diag && (mt * 16 + quad * 4 + r > lq)) s = -1e30f;
          sv[mt * 4 + r] = s;
          mx = fmaxf(mx, s);
        }
      }
      mx = fmaxf(mx, __shfl_xor(mx, 16, 64));
      mx = fmaxf(mx, __shfl_xor(mx, 32, 64));
      float mnew = fmaxf(mprev, mx);
      float alpha = exp2f(mprev - mnew);
      mprev = mnew;
      float rs = 0.f;
      #pragma unroll
      for (int mt = 0; mt < 4; mt++){
        float p0 = exp2f(sv[mt * 4 + 0] - mnew);
        float p1 = exp2f(sv[mt * 4 + 1] - mnew);
        float p2 = exp2f(sv[mt * 4 + 2] - mnew);
        float p3 = exp2f(sv[mt * 4 + 3] - mnew);
        rs += p0 + p1 + p2 + p3;
        union { uint2 u; __hip_bfloat162 h2[2]; } pk;
        pk.h2[0] = __float22bfloat162_rn(make_float2(p0, p1));
        pk.h2[1] = __float22bfloat162_rn(make_float2(p2, p3));
        *(uint2*)&Ps[(w * 16 + l16) * LD + mt * 16 + quad * 4] = pk.u;
      }
      rs += __shfl_xor(rs, 16, 64);
      rs += __shfl_xor(rs, 32, 64);
      lsum = lsum * alpha + rs;
      #pragma unroll
      for (int dt = 0; dt < 4; dt++) oacc[dt] *= alpha;

      #pragma unroll
      for (int ks = 0; ks < 2; ks++){
        bf16x8 pf = *(const bf16x8*)&Ps[(w * 16 + l16) * LD + ks * 32 + quad * 8];
        #pragma unroll
        for (int dt = 0; dt < 4; dt++){
          bf16x8 vf = *(const bf16x8*)&Vs[(dt * 16 + l16) * LD + ks * 32 + quad * 8];
          oacc[dt] = __builtin_amdgcn_mfma_f32_16x16x32_bf16(vf, pf, oacc[dt], 0, 0, 0);
        }
      }
    }

    float inv = 1.f / lsum;
    #pragma unroll
    for (int dt = 0; dt < 4; dt++){
      union { uint2 u; __hip_bfloat162 h2[2]; } ov;
      ov.h2[0] = __float22bfloat162_rn(make_float2(oacc[dt][0] * inv, oacc[dt][1] * inv));
      ov.h2[1] = __float22bfloat162_rn(make_float2(oacc[dt][2] * inv, oacc[dt][3] * inv));
      *(uint2*)(out + (bL + qrow) * 1024 + h * 64 + dt * 16 + quad * 4) = ov.u;
    }
  }
}

// ---------------- host launch ----------------
extern "C" void kernel_launch(void* const* d_in, const int* in_sizes, int n_in,
                              void* d_out, int out_size, void* d_ws, size_t ws_size,
                              hipStream_t stream){
  const float* x     = (const float*)d_in[0];
  const float* ln1_w = (const float*)d_in[1];
  const float* q_w   = (const float*)d_in[2];
  const float* kvd_w = (const float*)d_in[3];
  const float* kvn_w = (const float*)d_in[4];
  const float* kvu_w = (const float*)d_in[5];
  const float* o_w   = (const float*)d_in[6];
  const float* ln2_w = (const float*)d_in[7];
  const float* gate_w= (const float*)d_in[8];
  const float* sh_w1 = (const float*)d_in[9];
  const float* sh_w2 = (const float*)d_in[10];
  const float* sh_w3 = (const float*)d_in[11];
  const float* re_w1 = (const float*)d_in[12];
  const float* re_w2 = (const float*)d_in[13];
  const float* re_w3 = (const float*)d_in[14];
  float* out = (float*)d_out;

  char* wp = (char*)d_ws;
  auto alloc = [&](size_t bytes)->char*{
    char* p = wp; wp += (bytes + 255) & ~(size_t)255; return p;
  };
  u16* qkvdT = (u16*)alloc((size_t)1280 * 1024 * 2);   // q rows 0..1023, kvd 1024..1279
  u16* kvuT  = (u16*)alloc((size_t)2048 * 256 * 2);
  u16* oT    = (u16*)alloc((size_t)1024 * 1024 * 2);
  u16* sh13T = (u16*)alloc((size_t)2048 * 1024 * 2);   // interleaved w1/w3 rows
  u16* sh2T  = (u16*)alloc((size_t)1024 * 1024 * 2);
  u16* re13T = (u16*)alloc((size_t)8 * 2048 * 1024 * 2); // interleaved per expert
  u16* re2T  = (u16*)alloc((size_t)8 * 1024 * 1024 * 2);
  u16* xn    = (u16*)alloc((size_t)Tt * 1024 * 2);     // xn, later hn
  u16* qbuf  = (u16*)alloc((size_t)Tt * 1024 * 2);
  float* latpre = (float*)alloc((size_t)Tt * 256 * 4); // fp32 (routing-critical)
  u16* lat   = (u16*)alloc((size_t)Tt * 256 * 2);
  u16* kvbuf = (u16*)alloc((size_t)Tt * 2048 * 2);     // kv, later shared g [T,1024]
  u16* attnb = (u16*)alloc((size_t)Tt * 1024 * 2);
  float* hbuf = (float*)alloc((size_t)Tt * 1024 * 4);
  u16* vtb   = (u16*)alloc((size_t)Bb * Hh * 64 * Ll * 2);
  u16* gr    = (u16*)alloc((size_t)Tt * 2 * 1024 * 2); // routed g [2T,1024]
  int* counts = (int*)alloc(32);
  int* cur    = (int*)alloc(32);
  int* topi   = (int*)alloc((size_t)Tt * 2 * 4);
  float* topw = (float*)alloc((size_t)Tt * 2 * 4);
  int* entries= (int*)alloc((size_t)Tt * 2 * 4);
  float* ewt  = (float*)alloc((size_t)Tt * 2 * 4);
  (void)ws_size; (void)n_in; (void)in_sizes; (void)out_size;

  hipMemsetAsync(counts, 0, 32, stream);
  hipMemsetAsync(cur, 0, 32, stream);

  dim3 tb(32, 8);
  transpose5<<<dim3(32, 32, 5), tb, 0, stream>>>(q_w, o_w, sh_w1, sh_w3, sh_w2,
                                                 qkvdT, oT, sh13T, sh2T);
  transpose_conv<<<dim3(8, 32, 1), tb, 0, stream>>>(kvd_w, qkvdT, 1024, 256, 1024);
  transpose_conv<<<dim3(64, 8, 1), tb, 0, stream>>>(kvu_w, kvuT, 256, 2048, 0);
  transposeEx<<<dim3(32, 32, 24), tb, 0, stream>>>(re_w1, re_w3, re_w2, re13T, re2T);

  // xn = rmsnorm(x, ln1_w)
  rmsnorm_kernel<1024><<<Tt, 256, 0, stream>>>(x, ln1_w, xn);

  // [q(bf16) | latent_pre(fp32)] = xn @ [q_w | kvd_w]
  gemm_bt<64,0,5><<<dim3(10, 64), 256, 0, stream>>>(xn, qkvdT, qbuf, nullptr,
      Tt, 1280, 1024, 1024, 1024, nullptr, nullptr, nullptr, latpre);
  rmsnorm_kernel<256><<<Tt, 256, 0, stream>>>(latpre, kvn_w, lat);
  // kv = latent @ kvu_w
  gemm_bt<128,0,0><<<dim3(16, 32), 256, 0, stream>>>(lat, kvuT, kvbuf, nullptr,
      Tt, 2048, 256, 256, 2048, nullptr, nullptr, nullptr, nullptr);
  // attention
  vt_kernel<<<dim3(32, 16, 2), 256, 0, stream>>>(kvbuf, vtb);
  attn_kernel<<<dim3(16, 16, 2), 256, 0, stream>>>(qbuf, kvbuf, vtb, attnb);
  // h = x + attn_out @ o_w
  gemm_bt<64,0,1><<<dim3(8, 64), 256, 0, stream>>>(attnb, oT, hbuf, x,
      Tt, 1024, 1024, 1024, 1024, nullptr, nullptr, nullptr, nullptr);
  // router (also writes hn into xn)
  router_kernel<<<Tt, 256, 0, stream>>>(hbuf, ln2_w, gate_w, out + (size_t)Tt * Dd,
                                        topi, topw, xn);
  hist_kernel<<<16, 256, 0, stream>>>(topi, counts);
  bucket_kernel<<<16, 256, 0, stream>>>(topi, topw, counts, cur, entries, ewt);

  // shared expert: g = swiglu(hn @ [w1|w3] interleaved)  -> kvbuf [T,1024]
  gemm_bt<128,0,6><<<dim3(16, 32), 256, 0, stream>>>(xn, sh13T, kvbuf, nullptr,
      Tt, 2048, 1024, 1024, 1024, nullptr, nullptr, nullptr, nullptr);
  // out = h + g @ w2
  gemm_bt<64,0,1><<<dim3(8, 64), 256, 0, stream>>>(kvbuf, sh2T, out, hbuf,
      Tt, 1024, 1024, 1024, 1024, nullptr, nullptr, nullptr, nullptr);

  // routed: gr = swiglu(gather(hn) @ [w1|w3]e); out += w * (gr @ w2e)
  gemm_bt<128,1,6><<<dim3(16, 32, 8), 256, 0, stream>>>(xn, re13T, gr, nullptr,
      Tt, 2048, 1024, 1024, 1024, entries, nullptr, counts, nullptr);
  gemm_bt<128,2,4><<<dim3(8, 32, 8), 256, 0, stream>>>(gr, re2T, nullptr, nullptr,
      Tt, 1024, 1024, 1024, 1024, entries, ewt, counts, out);
}